// Round 1
// baseline (458.390 us; speedup 1.0000x reference)
//
#include <hip/hip_runtime.h>
#include <hip/hip_bf16.h>
#include <cstdint>

// Problem constants: B=64, N=1024, L=512, D=512, T=2, P=512, K_top=30
// out rows: [0,65536) = hx (t,b,p); [65536,131072) = hv tiled; then 1024*30 topk idx (as float)
// ws usage ~83 MB.

typedef float f32x4 __attribute__((ext_vector_type(4)));
typedef __bf16 bf16x8 __attribute__((ext_vector_type(8)));
typedef short short8 __attribute__((ext_vector_type(8)));

__device__ __forceinline__ short f2bf(float f) {
  union { float f; unsigned u; } x; x.f = f;
  unsigned r = x.u + 0x7fffu + ((x.u >> 16) & 1u);
  return (short)(r >> 16);
}

// ---------------- convert x [B,N,L] f32 -> xbf [T, B*P, L] bf16 ----------------
__global__ __launch_bounds__(256) void k_convert_x(const float* __restrict__ x,
                                                   short* __restrict__ xbf) {
  long e = (long)blockIdx.x * 256 + threadIdx.x;  // 8-elem chunk id, total 4194304
  int c8 = (int)(e & 63);
  long row = e >> 6;            // [0, 65536)
  int t = (int)(row >> 15);
  int rr = (int)(row & 32767);
  int b = rr >> 9, p = rr & 511;
  const float* src = x + (((long)b * 1024 + t * 512 + p) * 512 + c8 * 8);
  float4 f0 = *(const float4*)src;
  float4 f1 = *(const float4*)(src + 4);
  short8 o;
  o[0]=f2bf(f0.x); o[1]=f2bf(f0.y); o[2]=f2bf(f0.z); o[3]=f2bf(f0.w);
  o[4]=f2bf(f1.x); o[5]=f2bf(f1.y); o[6]=f2bf(f1.z); o[7]=f2bf(f1.w);
  *(short8*)(xbf + row * 512 + c8 * 8) = o;
}

// ---------------- transpose+convert weights: W[T,R,C] f32 -> Wt[T,C,R] bf16 ----------------
__global__ void k_transpose_w(const float* __restrict__ W, short* __restrict__ Wt,
                              int R, int C) {
  int c = blockIdx.x * 16 + (threadIdx.x & 15);
  int r = blockIdx.y * 16 + (threadIdx.x >> 4);
  long base = (long)blockIdx.z * R * C;
  Wt[base + (long)c * R + r] = f2bf(W[base + (long)r * C + c]);
}

// ---------------- column stats (sum, sumsq) over row chunks; C=512 ----------------
__global__ __launch_bounds__(512) void k_colstats(const float* __restrict__ src,
                                                  long matStride, int rowsPerChunk,
                                                  float* __restrict__ partial) {
  const int C = 512;
  int chunk = blockIdx.x, mat = blockIdx.y, nch = gridDim.x;
  int c = threadIdx.x;
  const float* p = src + (long)mat * matStride + (long)chunk * rowsPerChunk * C + c;
  float s = 0.f, q = 0.f;
  for (int r = 0; r < rowsPerChunk; ++r) {
    float v = p[(long)r * C];
    s += v; q = fmaf(v, v, q);
  }
  partial[(((long)mat * nch + chunk) * 2 + 0) * C + c] = s;
  partial[(((long)mat * nch + chunk) * 2 + 1) * C + c] = q;
}

// ---------------- reduce partials -> per-column scale/shift ----------------
__global__ void k_colreduce(const float* __restrict__ partial, int nchunks, float invR,
                            const float* __restrict__ gamma, const float* __restrict__ beta,
                            int gbStride, float* __restrict__ ss) {
  const int C = 512;
  int mat = blockIdx.y;
  int c = blockIdx.x * blockDim.x + threadIdx.x;
  float s = 0.f, q = 0.f;
  for (int k = 0; k < nchunks; ++k) {
    s += partial[(((long)mat * nchunks + k) * 2 + 0) * C + c];
    q += partial[(((long)mat * nchunks + k) * 2 + 1) * C + c];
  }
  float mu = s * invR;
  float var = fmaxf(q * invR - mu * mu, 0.f);
  float rinv = rsqrtf(var + 1e-5f);
  float g = gamma[(long)mat * gbStride + c];
  float b = beta[(long)mat * gbStride + c];
  float scale = rinv * g;
  ss[(mat * 2 + 0) * C + c] = scale;
  ss[(mat * 2 + 1) * C + c] = b - mu * scale;
}

// ---------------- v = BN(emb); vbf (bf16); vn = v/(||v||+1e-8) ----------------
__global__ __launch_bounds__(256) void k_compute_v(const float* __restrict__ emb,
                                                   const float* __restrict__ ss,
                                                   short* __restrict__ vbf,
                                                   float* __restrict__ vn) {
  __shared__ float red[256];
  int r = blockIdx.x, tid = threadIdx.x;
  float vals[2]; float sq = 0.f;
#pragma unroll
  for (int i = 0; i < 2; ++i) {
    int c = tid + i * 256;
    float xv = emb[(long)r * 512 + c];
    float val = fmaf(xv, ss[c], ss[512 + c]);
    vals[i] = val;
    sq = fmaf(val, val, sq);
    vbf[(long)r * 512 + c] = f2bf(val);
  }
  red[tid] = sq; __syncthreads();
  for (int s = 128; s > 0; s >>= 1) {
    if (tid < s) red[tid] += red[tid + s];
    __syncthreads();
  }
  float inv = 1.f / (sqrtf(red[0]) + 1e-8f);
#pragma unroll
  for (int i = 0; i < 2; ++i) {
    int c = tid + i * 256;
    vn[(long)r * 512 + c] = vals[i] * inv;
  }
}

// ---------------- bf16 MFMA GEMM: C[M,Ncols] = A[M,Kd] * Bt[Ncols,Kd]^T ----------------
#define LDSG(gp, lp) __builtin_amdgcn_global_load_lds(                     \
    (const __attribute__((address_space(1))) void*)(gp),                   \
    (__attribute__((address_space(3))) void*)(lp), 16, 0, 0)

__global__ __launch_bounds__(256, 2) void k_gemm_bf16(
    const short* __restrict__ A, const short* __restrict__ Bt, float* __restrict__ C,
    int tilesM, int tilesN, int nMats, int Kd, int Ncols,
    long aStride, long btStride, long cStride) {
  __shared__ short As[128 * 64];
  __shared__ short Bs[128 * 64];
  int id = blockIdx.x;
  int total = tilesM * tilesN * nMats;          // must be divisible by 8
  int perX = total >> 3;
  int w = (id & 7) * perX + (id >> 3);          // XCD-chunked swizzle
  int grp = tilesN * nMats;
  int mt = w / grp, rres = w % grp;
  int nt = rres % tilesN, mat = rres / tilesN;
  int m0 = mt * 128, n0 = nt * 128;
  const short* Ab = A + (long)mat * aStride + (long)m0 * Kd;
  const short* Bb = Bt + (long)mat * btStride + (long)n0 * Kd;
  float* Cb = C + (long)mat * cStride;
  int tid = threadIdx.x;
  int lane = tid & 63, wave = tid >> 6;
  int wr = (wave >> 1) * 64, wc = (wave & 1) * 64;
  f32x4 acc[4][4] = {};

  for (int kt = 0; kt < Kd; kt += 64) {
    __syncthreads();
#pragma unroll
    for (int i = 0; i < 4; ++i) {
      int c = (wave * 4 + i) * 64 + lane;       // phys 16B chunk in [0,1024)
      int row = c >> 3;
      int ccl = (c & 7) ^ (row & 7);            // inverse-swizzled source column
      LDSG(Ab + (long)row * Kd + kt + ccl * 8, As + (wave * 4 + i) * 512);
      LDSG(Bb + (long)row * Kd + kt + ccl * 8, Bs + (wave * 4 + i) * 512);
    }
    __syncthreads();
#pragma unroll
    for (int kk = 0; kk < 2; ++kk) {
      int k0 = kk * 32 + (lane >> 4) * 8;
      bf16x8 af[4], bfr[4];
#pragma unroll
      for (int m = 0; m < 4; ++m) {
        int row = wr + m * 16 + (lane & 15);
        int boff = (row * 128 + k0 * 2) ^ ((row & 7) << 4);
        af[m] = *reinterpret_cast<const bf16x8*>(reinterpret_cast<const char*>(As) + boff);
      }
#pragma unroll
      for (int n = 0; n < 4; ++n) {
        int row = wc + n * 16 + (lane & 15);
        int boff = (row * 128 + k0 * 2) ^ ((row & 7) << 4);
        bfr[n] = *reinterpret_cast<const bf16x8*>(reinterpret_cast<const char*>(Bs) + boff);
      }
#pragma unroll
      for (int m = 0; m < 4; ++m)
#pragma unroll
        for (int n = 0; n < 4; ++n)
          acc[m][n] = __builtin_amdgcn_mfma_f32_16x16x32_bf16(af[m], bfr[n], acc[m][n], 0, 0, 0);
    }
  }
#pragma unroll
  for (int m = 0; m < 4; ++m) {
    int row = m0 + wr + m * 16 + ((lane >> 4) << 2);
#pragma unroll
    for (int n = 0; n < 4; ++n) {
      int col = n0 + wc + n * 16 + (lane & 15);
#pragma unroll
      for (int j = 0; j < 4; ++j)
        Cb[(long)(row + j) * Ncols + col] = acc[m][n][j];
    }
  }
}

// ---------------- finalize hx in-place: out = out*scale + shift ----------------
__global__ __launch_bounds__(256) void k_finalize_hx(float* __restrict__ out,
                                                     const float* __restrict__ ss) {
  long idx = ((long)blockIdx.x * 256 + threadIdx.x) * 4;
  int c = (int)(idx & 511);
  int mat = (int)(idx >> 24);   // (idx>>9)>>15
  float4 vv = *(float4*)(out + idx);
  const float* sb = ss + mat * 1024;
  float4 sc = *(const float4*)(sb + c);
  float4 sh = *(const float4*)(sb + 512 + c);
  vv.x = fmaf(vv.x, sc.x, sh.x);
  vv.y = fmaf(vv.y, sc.y, sh.y);
  vv.z = fmaf(vv.z, sc.z, sh.z);
  vv.w = fmaf(vv.w, sc.w, sh.w);
  *(float4*)(out + idx) = vv;
}

// ---------------- finalize hv: BN + tile B=64 copies ----------------
__global__ __launch_bounds__(256) void k_finalize_hv(const float* __restrict__ hv,
                                                     const float* __restrict__ ss,
                                                     float* __restrict__ outhv) {
  int tp = blockIdx.x;                 // t*512 + p
  int mat = tp >> 9, p = tp & 511;
  int c = threadIdx.x * 2;
  float2 h = *(const float2*)(hv + (long)tp * 512 + c);
  const float* sb = ss + mat * 1024;
  float2 o;
  o.x = fmaf(h.x, sb[c], sb[512 + c]);
  o.y = fmaf(h.y, sb[c + 1], sb[512 + c + 1]);
  float* base = outhv + ((long)mat * 64 * 512 + p) * 512 + c;
  for (int b = 0; b < 64; ++b)
    *(float2*)(base + (long)b * 512 * 512) = o;
}

// ---------------- fp32 sim = vn @ vn^T (64x64 tiles) ----------------
__global__ __launch_bounds__(256) void k_sim_gemm(const float* __restrict__ vn,
                                                  float* __restrict__ sim) {
  __shared__ float a[64][17];
  __shared__ float b[64][17];
  int tid = threadIdx.x;
  int i0 = (blockIdx.x >> 4) * 64, j0 = (blockIdx.x & 15) * 64;
  float acc[4][4] = {};
  int srow = tid >> 2, sq = tid & 3;
  int tr = tid >> 4, tc = tid & 15;
  for (int k0 = 0; k0 < 512; k0 += 16) {
    __syncthreads();
    float4 va = *(const float4*)(vn + (long)(i0 + srow) * 512 + k0 + sq * 4);
    a[srow][sq * 4 + 0] = va.x; a[srow][sq * 4 + 1] = va.y;
    a[srow][sq * 4 + 2] = va.z; a[srow][sq * 4 + 3] = va.w;
    float4 vb = *(const float4*)(vn + (long)(j0 + srow) * 512 + k0 + sq * 4);
    b[srow][sq * 4 + 0] = vb.x; b[srow][sq * 4 + 1] = vb.y;
    b[srow][sq * 4 + 2] = vb.z; b[srow][sq * 4 + 3] = vb.w;
    __syncthreads();
#pragma unroll
    for (int k = 0; k < 16; ++k) {
      float ar[4], br[4];
#pragma unroll
      for (int i = 0; i < 4; ++i) ar[i] = a[tr * 4 + i][k];
#pragma unroll
      for (int j = 0; j < 4; ++j) br[j] = b[tc * 4 + j][k];
#pragma unroll
      for (int i = 0; i < 4; ++i)
#pragma unroll
        for (int j = 0; j < 4; ++j)
          acc[i][j] = fmaf(ar[i], br[j], acc[i][j]);
    }
  }
#pragma unroll
  for (int i = 0; i < 4; ++i)
#pragma unroll
    for (int j = 0; j < 4; ++j)
      sim[(long)(i0 + tr * 4 + i) * 1024 + j0 + tc * 4 + j] = acc[i][j];
}

// ---------------- top-30 per row (iterative select, tie -> lower index) ----------------
__global__ __launch_bounds__(256) void k_topk(const float* __restrict__ sim,
                                              float* __restrict__ outIdx) {
  __shared__ float vals[1024];
  __shared__ float sv[256];
  __shared__ int si[256];
  int n = blockIdx.x, tid = threadIdx.x;
  for (int i = tid; i < 1024; i += 256) vals[i] = sim[(long)n * 1024 + i];
  __syncthreads();
  for (int it = 0; it < 30; ++it) {
    float best = -1e30f; int bi = 1 << 30;
    for (int i = tid; i < 1024; i += 256) {
      float v = vals[i];
      if (v > best) { best = v; bi = i; }
    }
    sv[tid] = best; si[tid] = bi;
    __syncthreads();
    for (int s = 128; s > 0; s >>= 1) {
      if (tid < s) {
        float ov = sv[tid + s]; int oi = si[tid + s];
        if (ov > sv[tid] || (ov == sv[tid] && oi < si[tid])) { sv[tid] = ov; si[tid] = oi; }
      }
      __syncthreads();
    }
    if (tid == 0) {
      outIdx[(long)n * 30 + it] = (float)si[0];
      vals[si[0]] = -1e30f;
    }
    __syncthreads();
  }
}

extern "C" void kernel_launch(void* const* d_in, const int* in_sizes, int n_in,
                              void* d_out, int out_size, void* d_ws, size_t ws_size,
                              hipStream_t stream) {
  (void)in_sizes; (void)n_in; (void)out_size; (void)ws_size;
  const float* x     = (const float*)d_in[0];
  const float* emb   = (const float*)d_in[1];
  const float* emb_g = (const float*)d_in[2];
  const float* emb_b = (const float*)d_in[3];
  const float* Wx    = (const float*)d_in[4];
  // d_in[5] = bx : cancels in BN
  const float* gx_g  = (const float*)d_in[6];
  const float* gx_b  = (const float*)d_in[7];
  const float* Wv    = (const float*)d_in[8];
  // d_in[9] = bv : cancels in BN
  const float* gv_g  = (const float*)d_in[10];
  const float* gv_b  = (const float*)d_in[11];
  float* out = (float*)d_out;

  char* ws = (char*)d_ws;
  short* xbf = (short*)ws;  ws += 65536L * 512 * 2;   // 67.1 MB
  short* Wxt = (short*)ws;  ws += 2L * 512 * 512 * 2; // 1 MB
  short* Wvt = (short*)ws;  ws += 2L * 512 * 512 * 2; // 1 MB
  short* vbf = (short*)ws;  ws += 1024L * 512 * 2;    // 1 MB
  float* vn  = (float*)ws;  ws += 1024L * 512 * 4;    // 2 MB
  float* sim = (float*)ws;  ws += 1024L * 1024 * 4;   // 4 MB
  float* hvr = (float*)ws;  ws += 2L * 512 * 512 * 4; // 2 MB
  float* part= (float*)ws;  ws += 2L * 256 * 2 * 512 * 4; // 2 MB
  float* ssE = (float*)ws;  ws += 2L * 512 * 4;
  float* ssX = (float*)ws;  ws += 4L * 512 * 4;
  float* ssV = (float*)ws;  ws += 4L * 512 * 4;

  // x -> bf16 [T, B*P, L]
  k_convert_x<<<16384, 256, 0, stream>>>(x, xbf);
  // weights -> transposed bf16
  k_transpose_w<<<dim3(32, 32, 2), 256, 0, stream>>>(Wx, Wxt, 512, 512);
  k_transpose_w<<<dim3(32, 32, 2), 256, 0, stream>>>(Wv, Wvt, 512, 512);
  // emb BN -> vbf, vn
  k_colstats<<<dim3(8, 1), 512, 0, stream>>>(emb, 0L, 128, part);
  k_colreduce<<<dim3(2, 1), 256, 0, stream>>>(part, 8, 1.f / 1024.f, emb_g, emb_b, 0, ssE);
  k_compute_v<<<1024, 256, 0, stream>>>(emb, ssE, vbf, vn);
  // hx GEMM -> out rows [0, 65536), then BN in-place
  k_gemm_bf16<<<2048, 256, 0, stream>>>(xbf, Wxt, out, 256, 4, 2, 512, 512,
                                        32768L * 512, 512L * 512, 32768L * 512);
  k_colstats<<<dim3(256, 2), 512, 0, stream>>>(out, 32768L * 512, 128, part);
  k_colreduce<<<dim3(2, 2), 256, 0, stream>>>(part, 256, 1.f / 32768.f, gx_g, gx_b, 512, ssX);
  k_finalize_hx<<<32768, 256, 0, stream>>>(out, ssX);
  // hv GEMM (distinct rows only) -> BN -> tiled write
  k_gemm_bf16<<<32, 256, 0, stream>>>(vbf, Wvt, hvr, 4, 4, 2, 512, 512,
                                      512L * 512, 512L * 512, 512L * 512);
  k_colstats<<<dim3(4, 2), 512, 0, stream>>>(hvr, 512L * 512, 128, part);
  k_colreduce<<<dim3(2, 2), 256, 0, stream>>>(part, 4, 1.f / 512.f, gv_g, gv_b, 512, ssV);
  k_finalize_hv<<<1024, 256, 0, stream>>>(hvr, ssV, out + 65536L * 512);
  // cosine kNN
  k_sim_gemm<<<256, 256, 0, stream>>>(vn, sim);
  k_topk<<<1024, 256, 0, stream>>>(sim, out + 131072L * 512);
}

// Round 2
// 342.584 us; speedup vs baseline: 1.3380x; 1.3380x over previous
//
#include <hip/hip_runtime.h>
#include <hip/hip_bf16.h>
#include <cstdint>

// B=64, N=1024, L=512, D=512, T=2, P=512, K_top=30
// out: rows [0,65536) hx ; [65536,131072) hv tiled ; then 1024*30 topk idx (float)

typedef float f32x4 __attribute__((ext_vector_type(4)));
typedef __bf16 bf16x8 __attribute__((ext_vector_type(8)));
typedef short short8 __attribute__((ext_vector_type(8)));

__device__ __forceinline__ short f2bf(float f) {
  union { float f; unsigned u; } x; x.f = f;
  unsigned r = x.u + 0x7fffu + ((x.u >> 16) & 1u);
  return (short)(r >> 16);
}
__device__ __forceinline__ float bf2f(short s) {
  union { unsigned u; float f; } x; x.u = ((unsigned)(unsigned short)s) << 16;
  return x.f;
}

#define LDSG(gp, lp) __builtin_amdgcn_global_load_lds(                     \
    (const __attribute__((address_space(1))) void*)(gp),                   \
    (__attribute__((address_space(3))) void*)(lp), 16, 0, 0)

// ---------------- merged weight transpose+convert: z<2 -> Wx, else Wv ----------------
__global__ void k_transpose_w(const float* __restrict__ Wx, const float* __restrict__ Wv,
                              short* __restrict__ Wxt, short* __restrict__ Wvt) {
  int z = blockIdx.z;
  const float* W = (z < 2) ? (Wx + (long)z * 512 * 512) : (Wv + (long)(z - 2) * 512 * 512);
  short* Wt = (z < 2) ? (Wxt + (long)z * 512 * 512) : (Wvt + (long)(z - 2) * 512 * 512);
  int c = blockIdx.x * 16 + (threadIdx.x & 15);
  int r = blockIdx.y * 16 + (threadIdx.x >> 4);
  Wt[(long)c * 512 + r] = f2bf(W[(long)r * 512 + c]);
}

// ---------------- column stats (sum,sumsq) over row chunks; C=512 ----------------
__global__ __launch_bounds__(512) void k_colstats(const float* __restrict__ src,
                                                  int rowsPerChunk,
                                                  float* __restrict__ partial) {
  int chunk = blockIdx.x;
  int c = threadIdx.x;
  const float* p = src + (long)chunk * rowsPerChunk * 512 + c;
  float s = 0.f, q = 0.f;
  for (int r = 0; r < rowsPerChunk; ++r) {
    float v = p[(long)r * 512];
    s += v; q = fmaf(v, v, q);
  }
  partial[((long)chunk * 2 + 0) * 512 + c] = s;
  partial[((long)chunk * 2 + 1) * 512 + c] = q;
}

// ---------------- reduce hx partials -> per-column scale/shift ----------------
__global__ void k_colreduce(const float* __restrict__ partial, int nchunks, float invR,
                            const float* __restrict__ gamma, const float* __restrict__ beta,
                            float* __restrict__ ss) {
  int mat = blockIdx.y;
  int c = blockIdx.x * blockDim.x + threadIdx.x;
  float s = 0.f, q = 0.f;
  for (int k = 0; k < nchunks; ++k) {
    s += partial[(((long)mat * nchunks + k) * 2 + 0) * 512 + c];
    q += partial[(((long)mat * nchunks + k) * 2 + 1) * 512 + c];
  }
  float mu = s * invR;
  float var = fmaxf(q * invR - mu * mu, 0.f);
  float scale = rsqrtf(var + 1e-5f) * gamma[(long)mat * 512 + c];
  ss[(mat * 2 + 0) * 512 + c] = scale;
  ss[(mat * 2 + 1) * 512 + c] = beta[(long)mat * 512 + c] - mu * scale;
}

// ---------------- v = BN(emb) (fused stat-reduce); vbf bf16; vn normalized ----------------
__global__ __launch_bounds__(256) void k_compute_v(const float* __restrict__ emb,
                                                   const float* __restrict__ pstatsE,
                                                   const float* __restrict__ gamma,
                                                   const float* __restrict__ beta,
                                                   short* __restrict__ vbf,
                                                   float* __restrict__ vn) {
  __shared__ float ssl[1024];
  __shared__ float red[256];
  int r = blockIdx.x, tid = threadIdx.x;
#pragma unroll
  for (int i = 0; i < 2; ++i) {
    int c = tid + i * 256;
    float s = 0.f, q = 0.f;
#pragma unroll
    for (int k = 0; k < 8; ++k) {
      s += pstatsE[(k * 2 + 0) * 512 + c];
      q += pstatsE[(k * 2 + 1) * 512 + c];
    }
    float mu = s * (1.f / 1024.f);
    float var = fmaxf(q * (1.f / 1024.f) - mu * mu, 0.f);
    float scale = rsqrtf(var + 1e-5f) * gamma[c];
    ssl[c] = scale;
    ssl[512 + c] = beta[c] - mu * scale;
  }
  __syncthreads();
  float vals[2]; float sq = 0.f;
#pragma unroll
  for (int i = 0; i < 2; ++i) {
    int c = tid + i * 256;
    float xv = emb[(long)r * 512 + c];
    float val = fmaf(xv, ssl[c], ssl[512 + c]);
    vals[i] = val;
    sq = fmaf(val, val, sq);
    vbf[(long)r * 512 + c] = f2bf(val);
  }
  red[tid] = sq; __syncthreads();
  for (int s = 128; s > 0; s >>= 1) {
    if (tid < s) red[tid] += red[tid + s];
    __syncthreads();
  }
  float inv = 1.f / (sqrtf(red[0]) + 1e-8f);
#pragma unroll
  for (int i = 0; i < 2; ++i) {
    int c = tid + i * 256;
    vn[(long)r * 512 + c] = vals[i] * inv;
  }
}

// ---------------- hx GEMM: fused f32->bf16 A-staging, bf16 C, fused col-stats ----------------
__global__ __launch_bounds__(256, 2) void k_gemm_hx(
    const float* __restrict__ x, const short* __restrict__ Wxt,
    short* __restrict__ Cbf, float* __restrict__ pstats) {
  __shared__ short As[128 * 64];
  __shared__ short Bs[128 * 64];
  __shared__ float csw[2][2][128];
  int id = blockIdx.x;
  int w = (id & 7) * 256 + (id >> 3);   // XCD-chunked; 4 consecutive blocks share A-panel
  int mt = w >> 3, rres = w & 7;
  int nt = rres & 3, mat = rres >> 2;
  int m0 = mt * 128, n0 = nt * 128;
  int tid = threadIdx.x, lane = tid & 63, wave = tid >> 6;
  int wr = (wave >> 1) * 64, wc = (wave & 1) * 64;
  const short* Bb = Wxt + (long)mat * 512 * 512 + (long)n0 * 512;
  f32x4 acc[4][4] = {};

  for (int kt = 0; kt < 512; kt += 64) {
    __syncthreads();
#pragma unroll
    for (int i = 0; i < 4; ++i) {
      int c = (wave * 4 + i) * 64 + lane;
      int row = c >> 3;
      int ccl = (c & 7) ^ (row & 7);
      LDSG(Bb + (long)row * 512 + kt + ccl * 8, Bs + (wave * 4 + i) * 512);
    }
#pragma unroll
    for (int i = 0; i < 4; ++i) {
      int c = i * 256 + tid;            // 1024 8-float chunks of the 128x64 f32 A tile
      int row = c >> 3, g = c & 7;
      int rr = m0 + row;
      int b = rr >> 9, p = rr & 511;
      const float* src = x + ((long)(b * 1024 + mat * 512 + p)) * 512 + kt + g * 8;
      f32x4 f0 = *(const f32x4*)src;
      f32x4 f1 = *(const f32x4*)(src + 4);
      short8 o;
      o[0]=f2bf(f0[0]); o[1]=f2bf(f0[1]); o[2]=f2bf(f0[2]); o[3]=f2bf(f0[3]);
      o[4]=f2bf(f1[0]); o[5]=f2bf(f1[1]); o[6]=f2bf(f1[2]); o[7]=f2bf(f1[3]);
      int boff = (row * 128 + g * 16) ^ ((row & 7) << 4);
      *(short8*)((char*)As + boff) = o;
    }
    __syncthreads();
#pragma unroll
    for (int kk = 0; kk < 2; ++kk) {
      int k0 = kk * 32 + (lane >> 4) * 8;
      bf16x8 af[4], bfr[4];
#pragma unroll
      for (int m = 0; m < 4; ++m) {
        int row = wr + m * 16 + (lane & 15);
        int boff = (row * 128 + k0 * 2) ^ ((row & 7) << 4);
        af[m] = *reinterpret_cast<const bf16x8*>((const char*)As + boff);
      }
#pragma unroll
      for (int n = 0; n < 4; ++n) {
        int row = wc + n * 16 + (lane & 15);
        int boff = (row * 128 + k0 * 2) ^ ((row & 7) << 4);
        bfr[n] = *reinterpret_cast<const bf16x8*>((const char*)Bs + boff);
      }
#pragma unroll
      for (int m = 0; m < 4; ++m)
#pragma unroll
        for (int n = 0; n < 4; ++n)
          acc[m][n] = __builtin_amdgcn_mfma_f32_16x16x32_bf16(af[m], bfr[n], acc[m][n], 0, 0, 0);
    }
  }
  short* Cb = Cbf + (long)mat * 32768 * 512;
#pragma unroll
  for (int n = 0; n < 4; ++n) {
    int col = n0 + wc + n * 16 + (lane & 15);
    float s = 0.f, q = 0.f;
#pragma unroll
    for (int m = 0; m < 4; ++m) {
      int row = m0 + wr + m * 16 + ((lane >> 4) << 2);
#pragma unroll
      for (int j = 0; j < 4; ++j) {
        float v = acc[m][n][j];
        s += v; q = fmaf(v, v, q);
        Cb[(long)(row + j) * 512 + col] = f2bf(v);
      }
    }
    s += __shfl_xor(s, 16); s += __shfl_xor(s, 32);
    q += __shfl_xor(q, 16); q += __shfl_xor(q, 32);
    if (lane < 16) {
      csw[0][wave >> 1][wc + n * 16 + lane] = s;
      csw[1][wave >> 1][wc + n * 16 + lane] = q;
    }
  }
  __syncthreads();
  {
    int v = tid >> 7, cl = tid & 127;
    pstats[(((long)mat * 256 + mt) * 2 + v) * 512 + n0 + cl] =
        csw[v][0][cl] + csw[v][1][cl];
  }
}

// ---------------- hv GEMM (small): bf16 in, f32 out, fused col-stats ----------------
__global__ __launch_bounds__(256, 2) void k_gemm_hv(
    const short* __restrict__ vbf, const short* __restrict__ Wvt,
    float* __restrict__ hvr, float* __restrict__ pstats) {
  __shared__ short As[128 * 64];
  __shared__ short Bs[128 * 64];
  __shared__ float csw[2][2][128];
  int id = blockIdx.x;                  // 32 blocks: mt*8 + nt*2 + mat
  int mt = id >> 3, nt = (id >> 1) & 3, mat = id & 1;
  int m0 = mt * 128, n0 = nt * 128;
  int tid = threadIdx.x, lane = tid & 63, wave = tid >> 6;
  int wr = (wave >> 1) * 64, wc = (wave & 1) * 64;
  const short* Ab = vbf + ((long)mat * 512 + m0) * 512;
  const short* Bb = Wvt + (long)mat * 512 * 512 + (long)n0 * 512;
  f32x4 acc[4][4] = {};

  for (int kt = 0; kt < 512; kt += 64) {
    __syncthreads();
#pragma unroll
    for (int i = 0; i < 4; ++i) {
      int c = (wave * 4 + i) * 64 + lane;
      int row = c >> 3;
      int ccl = (c & 7) ^ (row & 7);
      LDSG(Ab + (long)row * 512 + kt + ccl * 8, As + (wave * 4 + i) * 512);
      LDSG(Bb + (long)row * 512 + kt + ccl * 8, Bs + (wave * 4 + i) * 512);
    }
    __syncthreads();
#pragma unroll
    for (int kk = 0; kk < 2; ++kk) {
      int k0 = kk * 32 + (lane >> 4) * 8;
      bf16x8 af[4], bfr[4];
#pragma unroll
      for (int m = 0; m < 4; ++m) {
        int row = wr + m * 16 + (lane & 15);
        int boff = (row * 128 + k0 * 2) ^ ((row & 7) << 4);
        af[m] = *reinterpret_cast<const bf16x8*>((const char*)As + boff);
      }
#pragma unroll
      for (int n = 0; n < 4; ++n) {
        int row = wc + n * 16 + (lane & 15);
        int boff = (row * 128 + k0 * 2) ^ ((row & 7) << 4);
        bfr[n] = *reinterpret_cast<const bf16x8*>((const char*)Bs + boff);
      }
#pragma unroll
      for (int m = 0; m < 4; ++m)
#pragma unroll
        for (int n = 0; n < 4; ++n)
          acc[m][n] = __builtin_amdgcn_mfma_f32_16x16x32_bf16(af[m], bfr[n], acc[m][n], 0, 0, 0);
    }
  }
  float* Cb = hvr + (long)mat * 512 * 512;
#pragma unroll
  for (int n = 0; n < 4; ++n) {
    int col = n0 + wc + n * 16 + (lane & 15);
    float s = 0.f, q = 0.f;
#pragma unroll
    for (int m = 0; m < 4; ++m) {
      int row = m0 + wr + m * 16 + ((lane >> 4) << 2);
#pragma unroll
      for (int j = 0; j < 4; ++j) {
        float v = acc[m][n][j];
        s += v; q = fmaf(v, v, q);
        Cb[(long)(row + j) * 512 + col] = v;
      }
    }
    s += __shfl_xor(s, 16); s += __shfl_xor(s, 32);
    q += __shfl_xor(q, 16); q += __shfl_xor(q, 32);
    if (lane < 16) {
      csw[0][wave >> 1][wc + n * 16 + lane] = s;
      csw[1][wave >> 1][wc + n * 16 + lane] = q;
    }
  }
  __syncthreads();
  {
    int v = tid >> 7, cl = tid & 127;
    pstats[(((long)mat * 4 + mt) * 2 + v) * 512 + n0 + cl] =
        csw[v][0][cl] + csw[v][1][cl];
  }
}

// ---------------- finalize hx: bf16 C -> BN -> f32 out ----------------
__global__ __launch_bounds__(256) void k_finalize_hx(const short* __restrict__ Cbf,
                                                     const float* __restrict__ ss,
                                                     float* __restrict__ out) {
  long e = (long)blockIdx.x * 256 + threadIdx.x;   // 8-elem chunk
  long row = e >> 6;
  int c0 = (int)(e & 63) * 8;
  int mat = (int)(row >> 15);
  short8 h = *(const short8*)(Cbf + row * 512 + c0);
  const float* sb = ss + mat * 1024;
  f32x4 o0, o1;
#pragma unroll
  for (int j = 0; j < 4; ++j) o0[j] = fmaf(bf2f(h[j]), sb[c0 + j], sb[512 + c0 + j]);
#pragma unroll
  for (int j = 0; j < 4; ++j) o1[j] = fmaf(bf2f(h[4 + j]), sb[c0 + 4 + j], sb[512 + c0 + 4 + j]);
  *(f32x4*)(out + row * 512 + c0) = o0;
  *(f32x4*)(out + row * 512 + c0 + 4) = o1;
}

// ---------------- finalize hv: fused stat-reduce, BN, tile B=64 ----------------
__global__ __launch_bounds__(256) void k_finalize_hv(const float* __restrict__ hvr,
                                                     const float* __restrict__ pstatsV,
                                                     const float* __restrict__ gv_g,
                                                     const float* __restrict__ gv_b,
                                                     float* __restrict__ outhv) {
  __shared__ float ssl[1024];
  int tp = blockIdx.x, tid = threadIdx.x;
  int mat = tp >> 9;
#pragma unroll
  for (int i = 0; i < 2; ++i) {
    int c = tid + i * 256;
    float s = 0.f, q = 0.f;
#pragma unroll
    for (int k = 0; k < 4; ++k) {
      s += pstatsV[(((long)mat * 4 + k) * 2 + 0) * 512 + c];
      q += pstatsV[(((long)mat * 4 + k) * 2 + 1) * 512 + c];
    }
    float mu = s * (1.f / 512.f);
    float var = fmaxf(q * (1.f / 512.f) - mu * mu, 0.f);
    float scale = rsqrtf(var + 1e-5f) * gv_g[mat * 512 + c];
    ssl[c] = scale;
    ssl[512 + c] = gv_b[mat * 512 + c] - mu * scale;
  }
  __syncthreads();
  int p = tp & 511;
  int c = tid * 2;
  float2 h = *(const float2*)(hvr + (long)tp * 512 + c);
  float2 o;
  o.x = fmaf(h.x, ssl[c], ssl[512 + c]);
  o.y = fmaf(h.y, ssl[c + 1], ssl[512 + c + 1]);
  float* base = outhv + ((long)mat * 64 * 512 + p) * 512 + c;
  for (int b = 0; b < 64; ++b)
    *(float2*)(base + (long)b * 512 * 512) = o;
}

// ---------------- sim halves: k-major LDS, float4 frags, k-split x2 ----------------
__global__ __launch_bounds__(256) void k_sim(const float* __restrict__ vn,
                                             float* __restrict__ simP) {
  __shared__ float a[16][68];
  __shared__ float b[16][68];
  int tid = threadIdx.x;
  int tile = blockIdx.x >> 1, kh = blockIdx.x & 1;
  int i0 = (tile >> 4) * 64, j0 = (tile & 15) * 64;
  int srow = tid >> 2, sq = tid & 3;
  int tr = tid >> 4, tc = tid & 15;
  float acc[4][4] = {};
  for (int k0 = kh * 256; k0 < kh * 256 + 256; k0 += 16) {
    __syncthreads();
    f32x4 va = *(const f32x4*)(vn + (long)(i0 + srow) * 512 + k0 + sq * 4);
    f32x4 vb = *(const f32x4*)(vn + (long)(j0 + srow) * 512 + k0 + sq * 4);
#pragma unroll
    for (int j = 0; j < 4; ++j) { a[sq * 4 + j][srow] = va[j]; b[sq * 4 + j][srow] = vb[j]; }
    __syncthreads();
#pragma unroll
    for (int k = 0; k < 16; ++k) {
      f32x4 ar = *(const f32x4*)&a[k][tr * 4];
      f32x4 br = *(const f32x4*)&b[k][tc * 4];
#pragma unroll
      for (int i = 0; i < 4; ++i)
#pragma unroll
        for (int j = 0; j < 4; ++j)
          acc[i][j] = fmaf(ar[i], br[j], acc[i][j]);
    }
  }
  float* dst = simP + (long)kh * 1024 * 1024;
#pragma unroll
  for (int i = 0; i < 4; ++i) {
    f32x4 o;
#pragma unroll
    for (int j = 0; j < 4; ++j) o[j] = acc[i][j];
    *(f32x4*)(dst + (long)(i0 + tr * 4 + i) * 1024 + j0 + tc * 4) = o;
  }
}

// ---------------- top-30: one wave per row, registers + shfl butterfly ----------------
__global__ __launch_bounds__(256) void k_topk(const float* __restrict__ simP,
                                              float* __restrict__ outIdx) {
  int wv = threadIdx.x >> 6, lane = threadIdx.x & 63;
  int row = blockIdx.x * 4 + wv;
  const float* r0 = simP + (long)row * 1024;
  const float* r1 = r0 + 1024L * 1024;
  f32x4 v[4];
#pragma unroll
  for (int i = 0; i < 4; ++i) {
    f32x4 x0 = *(const f32x4*)(r0 + i * 256 + lane * 4);
    f32x4 x1 = *(const f32x4*)(r1 + i * 256 + lane * 4);
    v[i] = x0 + x1;
  }
  for (int it = 0; it < 30; ++it) {
    float bv = -1e30f; int bi = 1 << 30;
#pragma unroll
    for (int i = 0; i < 4; ++i)
#pragma unroll
      for (int j = 0; j < 4; ++j) {
        float val = v[i][j];
        if (val > bv) { bv = val; bi = i * 256 + lane * 4 + j; }
      }
#pragma unroll
    for (int off = 1; off < 64; off <<= 1) {
      float ov = __shfl_xor(bv, off);
      int oi = __shfl_xor(bi, off);
      if (ov > bv || (ov == bv && oi < bi)) { bv = ov; bi = oi; }
    }
    if (lane == 0) outIdx[(long)row * 30 + it] = (float)bi;
#pragma unroll
    for (int i = 0; i < 4; ++i)
#pragma unroll
      for (int j = 0; j < 4; ++j)
        if ((i * 256 + lane * 4 + j) == bi) v[i][j] = -1e30f;
  }
}

extern "C" void kernel_launch(void* const* d_in, const int* in_sizes, int n_in,
                              void* d_out, int out_size, void* d_ws, size_t ws_size,
                              hipStream_t stream) {
  (void)in_sizes; (void)n_in; (void)out_size; (void)ws_size;
  const float* x     = (const float*)d_in[0];
  const float* emb   = (const float*)d_in[1];
  const float* emb_g = (const float*)d_in[2];
  const float* emb_b = (const float*)d_in[3];
  const float* Wx    = (const float*)d_in[4];
  // d_in[5] = bx : cancels in BN
  const float* gx_g  = (const float*)d_in[6];
  const float* gx_b  = (const float*)d_in[7];
  const float* Wv    = (const float*)d_in[8];
  // d_in[9] = bv : cancels in BN
  const float* gv_g  = (const float*)d_in[10];
  const float* gv_b  = (const float*)d_in[11];
  float* out = (float*)d_out;

  char* ws = (char*)d_ws;
  short* hxr = (short*)ws;  ws += 65536L * 512 * 2;   // 67.1 MB (reused as simP later)
  short* Wxt = (short*)ws;  ws += 2L * 512 * 512 * 2;
  short* Wvt = (short*)ws;  ws += 2L * 512 * 512 * 2;
  short* vbf = (short*)ws;  ws += 1024L * 512 * 2;
  float* vn  = (float*)ws;  ws += 1024L * 512 * 4;
  float* hvr = (float*)ws;  ws += 2L * 512 * 512 * 4;
  float* pstatsX = (float*)ws; ws += 2L * 256 * 2 * 512 * 4;  // 2 MB
  float* pstatsE = (float*)ws; ws += 8L * 2 * 512 * 4;
  float* pstatsV = (float*)ws; ws += 2L * 4 * 2 * 512 * 4;
  float* ssX = (float*)ws;     ws += 4L * 512 * 4;
  float* simP = (float*)hxr;   // alias: valid after k_finalize_hx

  k_transpose_w<<<dim3(32, 32, 4), 256, 0, stream>>>(Wx, Wv, Wxt, Wvt);
  k_colstats<<<8, 512, 0, stream>>>(emb, 128, pstatsE);
  k_compute_v<<<1024, 256, 0, stream>>>(emb, pstatsE, emb_g, emb_b, vbf, vn);
  k_gemm_hx<<<2048, 256, 0, stream>>>(x, Wxt, hxr, pstatsX);
  k_colreduce<<<dim3(2, 2), 256, 0, stream>>>(pstatsX, 256, 1.f / 32768.f, gx_g, gx_b, ssX);
  k_finalize_hx<<<16384, 256, 0, stream>>>(hxr, ssX, out);
  k_gemm_hv<<<32, 256, 0, stream>>>(vbf, Wvt, hvr, pstatsV);
  k_finalize_hv<<<1024, 256, 0, stream>>>(hvr, pstatsV, gv_g, gv_b, out + 65536L * 512);
  k_sim<<<512, 256, 0, stream>>>(vn, simP);
  k_topk<<<256, 256, 0, stream>>>(simP, out + 131072L * 512);
}

// Round 3
// 324.657 us; speedup vs baseline: 1.4119x; 1.0552x over previous
//
#include <hip/hip_runtime.h>
#include <hip/hip_bf16.h>
#include <cstdint>

// B=64, N=1024, L=512, D=512, T=2, P=512, K_top=30
// out: rows [0,65536) hx ; [65536,131072) hv tiled ; then 1024*30 topk idx (float)

typedef float f32x4 __attribute__((ext_vector_type(4)));
typedef __bf16 bf16x8 __attribute__((ext_vector_type(8)));
typedef short short8 __attribute__((ext_vector_type(8)));
typedef short short4v __attribute__((ext_vector_type(4)));

__device__ __forceinline__ short f2bf(float f) {
  union { float f; unsigned u; } x; x.f = f;
  unsigned r = x.u + 0x7fffu + ((x.u >> 16) & 1u);
  return (short)(r >> 16);
}
__device__ __forceinline__ float bf2f(short s) {
  union { unsigned u; float f; } x; x.u = ((unsigned)(unsigned short)s) << 16;
  return x.f;
}

#define LDSG(gp, lp) __builtin_amdgcn_global_load_lds(                     \
    (const __attribute__((address_space(1))) void*)(gp),                   \
    (__attribute__((address_space(3))) void*)(lp), 16, 0, 0)

// ---------------- LDS-tiled weight transpose+convert: z<2 -> Wx, else Wv ----------------
__global__ __launch_bounds__(256) void k_transpose_w(
    const float* __restrict__ Wx, const float* __restrict__ Wv,
    short* __restrict__ Wxt, short* __restrict__ Wvt) {
  __shared__ float t[64][65];
  int z = blockIdx.z;
  const float* W = (z < 2) ? (Wx + (long)z * 262144) : (Wv + (long)(z - 2) * 262144);
  short* Wt = (z < 2) ? (Wxt + (long)z * 262144) : (Wvt + (long)(z - 2) * 262144);
  int r0 = blockIdx.y * 64, c0 = blockIdx.x * 64;
  int lr = threadIdx.x >> 4, lc = (threadIdx.x & 15) * 4;
#pragma unroll
  for (int p = 0; p < 4; ++p) {
    f32x4 v = *(const f32x4*)(W + (long)(r0 + lr + p * 16) * 512 + c0 + lc);
#pragma unroll
    for (int j = 0; j < 4; ++j) t[lr + p * 16][lc + j] = v[j];
  }
  __syncthreads();
  int wr = (threadIdx.x & 15) * 4;   // r within tile
  int wc = threadIdx.x >> 4;         // c within tile
#pragma unroll
  for (int p = 0; p < 4; ++p) {
    int c = wc + p * 16;
    short4v o;
#pragma unroll
    for (int j = 0; j < 4; ++j) o[j] = f2bf(t[wr + j][c]);
    *(short4v*)(Wt + (long)(c0 + c) * 512 + r0 + wr) = o;
  }
}

// ---------------- column stats (sum,sumsq) over row chunks; C=512 ----------------
__global__ __launch_bounds__(512) void k_colstats(const float* __restrict__ src,
                                                  int rowsPerChunk,
                                                  float* __restrict__ partial) {
  int chunk = blockIdx.x;
  int c = threadIdx.x;
  const float* p = src + (long)chunk * rowsPerChunk * 512 + c;
  float s = 0.f, q = 0.f;
  for (int r = 0; r < rowsPerChunk; ++r) {
    float v = p[(long)r * 512];
    s += v; q = fmaf(v, v, q);
  }
  partial[((long)chunk * 2 + 0) * 512 + c] = s;
  partial[((long)chunk * 2 + 1) * 512 + c] = q;
}

// ---------------- reduce partials -> per-column scale/shift ----------------
__global__ void k_colreduce(const float* __restrict__ partial, int nchunks, float invR,
                            const float* __restrict__ gamma, const float* __restrict__ beta,
                            int gbStride, float* __restrict__ ss) {
  int mat = blockIdx.y;
  int c = blockIdx.x * blockDim.x + threadIdx.x;
  float s = 0.f, q = 0.f;
  for (int k = 0; k < nchunks; ++k) {
    s += partial[(((long)mat * nchunks + k) * 2 + 0) * 512 + c];
    q += partial[(((long)mat * nchunks + k) * 2 + 1) * 512 + c];
  }
  float mu = s * invR;
  float var = fmaxf(q * invR - mu * mu, 0.f);
  float scale = rsqrtf(var + 1e-5f) * gamma[(long)mat * gbStride + c];
  ss[(mat * 2 + 0) * 512 + c] = scale;
  ss[(mat * 2 + 1) * 512 + c] = beta[(long)mat * gbStride + c] - mu * scale;
}

// ---------------- v = BN(emb) via ssE; vbf bf16; vn normalized ----------------
__global__ __launch_bounds__(256) void k_compute_v(const float* __restrict__ emb,
                                                   const float* __restrict__ ssE,
                                                   short* __restrict__ vbf,
                                                   float* __restrict__ vn) {
  __shared__ float red[256];
  int r = blockIdx.x, tid = threadIdx.x;
  float vals[2]; float sq = 0.f;
#pragma unroll
  for (int i = 0; i < 2; ++i) {
    int c = tid + i * 256;
    float xv = emb[(long)r * 512 + c];
    float val = fmaf(xv, ssE[c], ssE[512 + c]);
    vals[i] = val;
    sq = fmaf(val, val, sq);
    vbf[(long)r * 512 + c] = f2bf(val);
  }
  red[tid] = sq; __syncthreads();
  for (int s = 128; s > 0; s >>= 1) {
    if (tid < s) red[tid] += red[tid + s];
    __syncthreads();
  }
  float inv = 1.f / (sqrtf(red[0]) + 1e-8f);
#pragma unroll
  for (int i = 0; i < 2; ++i) {
    int c = tid + i * 256;
    vn[(long)r * 512 + c] = vals[i] * inv;
  }
}

// ---------------- hx GEMM: dbuf LDS, fused f32->bf16 A-staging, bf16 C, fused stats ----------------
__global__ __launch_bounds__(256, 2) void k_gemm_hx(
    const float* __restrict__ x, const short* __restrict__ Wxt,
    short* __restrict__ Cbf, float* __restrict__ pstats) {
  __shared__ short As[2][8192];
  __shared__ short Bs[2][8192];
  __shared__ float csw[2][2][128];
  int id = blockIdx.x;
  int w = (id & 7) * 256 + (id >> 3);   // XCD-chunked; nt/mat fastest share A-panel locality
  int mt = w >> 3, rres = w & 7;
  int nt = rres & 3, mat = rres >> 2;
  int m0 = mt * 128, n0 = nt * 128;
  int tid = threadIdx.x, lane = tid & 63, wave = tid >> 6;
  int wr = (wave >> 1) * 64, wc = (wave & 1) * 64;
  const short* Bb = Wxt + (long)mat * 262144 + (long)n0 * 512;

  const float* aSrc[4];
  int aOff[4];
#pragma unroll
  for (int i = 0; i < 4; ++i) {
    int c = i * 256 + tid;
    int row = c >> 3, g = c & 7;
    int rr = m0 + row;
    int b = rr >> 9, p = rr & 511;
    aSrc[i] = x + ((long)(b * 1024 + mat * 512 + p)) * 512 + g * 8;
    aOff[i] = (row * 128 + g * 16) ^ ((row & 7) << 4);
  }
  const short* bSrc[4];
  int ldsOff[4];
#pragma unroll
  for (int i = 0; i < 4; ++i) {
    int c = (wave * 4 + i) * 64 + lane;
    int row = c >> 3;
    int ccl = (c & 7) ^ (row & 7);
    bSrc[i] = Bb + (long)row * 512 + ccl * 8;
    ldsOff[i] = (wave * 4 + i) * 512;
  }
  f32x4 acc[4][4] = {};
  f32x4 a0[4], a1[4];

  // prologue: stage tile 0 into buffer 0
#pragma unroll
  for (int i = 0; i < 4; ++i) { a0[i] = *(const f32x4*)(aSrc[i]); a1[i] = *(const f32x4*)(aSrc[i] + 4); }
#pragma unroll
  for (int i = 0; i < 4; ++i) LDSG(bSrc[i], &Bs[0][ldsOff[i]]);
#pragma unroll
  for (int i = 0; i < 4; ++i) {
    short8 o;
#pragma unroll
    for (int j = 0; j < 4; ++j) { o[j] = f2bf(a0[i][j]); o[4 + j] = f2bf(a1[i][j]); }
    *(short8*)((char*)As[0] + aOff[i]) = o;
  }
  __syncthreads();

  int cur = 0;
  for (int t = 0; t < 8; ++t) {
    int kn = (t + 1) * 64;
    if (t < 7) {
#pragma unroll
      for (int i = 0; i < 4; ++i) {
        a0[i] = *(const f32x4*)(aSrc[i] + kn);
        a1[i] = *(const f32x4*)(aSrc[i] + kn + 4);
      }
#pragma unroll
      for (int i = 0; i < 4; ++i) LDSG(bSrc[i] + kn, &Bs[cur ^ 1][ldsOff[i]]);
    }
    const char* Ab_ = (const char*)As[cur];
    const char* Bb_ = (const char*)Bs[cur];
#pragma unroll
    for (int kk = 0; kk < 2; ++kk) {
      int k0 = kk * 32 + (lane >> 4) * 8;
      bf16x8 af[4], bfr[4];
#pragma unroll
      for (int m = 0; m < 4; ++m) {
        int row = wr + m * 16 + (lane & 15);
        int boff = (row * 128 + k0 * 2) ^ ((row & 7) << 4);
        af[m] = *reinterpret_cast<const bf16x8*>(Ab_ + boff);
      }
#pragma unroll
      for (int n = 0; n < 4; ++n) {
        int row = wc + n * 16 + (lane & 15);
        int boff = (row * 128 + k0 * 2) ^ ((row & 7) << 4);
        bfr[n] = *reinterpret_cast<const bf16x8*>(Bb_ + boff);
      }
#pragma unroll
      for (int m = 0; m < 4; ++m)
#pragma unroll
        for (int n = 0; n < 4; ++n)
          acc[m][n] = __builtin_amdgcn_mfma_f32_16x16x32_bf16(af[m], bfr[n], acc[m][n], 0, 0, 0);
    }
    if (t < 7) {
#pragma unroll
      for (int i = 0; i < 4; ++i) {
        short8 o;
#pragma unroll
        for (int j = 0; j < 4; ++j) { o[j] = f2bf(a0[i][j]); o[4 + j] = f2bf(a1[i][j]); }
        *(short8*)((char*)As[cur ^ 1] + aOff[i]) = o;
      }
    }
    __syncthreads();
    cur ^= 1;
  }
  short* Cb = Cbf + (long)mat * 32768 * 512;
#pragma unroll
  for (int n = 0; n < 4; ++n) {
    int col = n0 + wc + n * 16 + (lane & 15);
    float s = 0.f, q = 0.f;
#pragma unroll
    for (int m = 0; m < 4; ++m) {
      int row = m0 + wr + m * 16 + ((lane >> 4) << 2);
#pragma unroll
      for (int j = 0; j < 4; ++j) {
        float v = acc[m][n][j];
        s += v; q = fmaf(v, v, q);
        Cb[(long)(row + j) * 512 + col] = f2bf(v);
      }
    }
    s += __shfl_xor(s, 16); s += __shfl_xor(s, 32);
    q += __shfl_xor(q, 16); q += __shfl_xor(q, 32);
    if (lane < 16) {
      csw[0][wave >> 1][wc + n * 16 + lane] = s;
      csw[1][wave >> 1][wc + n * 16 + lane] = q;
    }
  }
  __syncthreads();
  {
    int v = tid >> 7, cl = tid & 127;
    pstats[(((long)mat * 256 + mt) * 2 + v) * 512 + n0 + cl] =
        csw[v][0][cl] + csw[v][1][cl];
  }
}

// ---------------- hv GEMM: dbuf LDS, bf16 in, f32 out, fused stats ----------------
__global__ __launch_bounds__(256, 2) void k_gemm_hv(
    const short* __restrict__ vbf, const short* __restrict__ Wvt,
    float* __restrict__ hvr, float* __restrict__ pstats) {
  __shared__ short As[2][8192];
  __shared__ short Bs[2][8192];
  __shared__ float csw[2][2][128];
  int id = blockIdx.x;                  // 32 blocks: mt*8 + nt*2 + mat
  int mt = id >> 3, nt = (id >> 1) & 3, mat = id & 1;
  int m0 = mt * 128, n0 = nt * 128;
  int tid = threadIdx.x, lane = tid & 63, wave = tid >> 6;
  int wr = (wave >> 1) * 64, wc = (wave & 1) * 64;
  const short* Ab = vbf + ((long)mat * 512 + m0) * 512;
  const short* Bb = Wvt + (long)mat * 262144 + (long)n0 * 512;
  const short* aS[4]; const short* bS[4]; int ldsOff[4];
#pragma unroll
  for (int i = 0; i < 4; ++i) {
    int c = (wave * 4 + i) * 64 + lane;
    int row = c >> 3;
    int ccl = (c & 7) ^ (row & 7);
    aS[i] = Ab + (long)row * 512 + ccl * 8;
    bS[i] = Bb + (long)row * 512 + ccl * 8;
    ldsOff[i] = (wave * 4 + i) * 512;
  }
  f32x4 acc[4][4] = {};
#pragma unroll
  for (int i = 0; i < 4; ++i) { LDSG(aS[i], &As[0][ldsOff[i]]); LDSG(bS[i], &Bs[0][ldsOff[i]]); }
  __syncthreads();
  int cur = 0;
  for (int t = 0; t < 8; ++t) {
    int kn = (t + 1) * 64;
    if (t < 7) {
#pragma unroll
      for (int i = 0; i < 4; ++i) {
        LDSG(aS[i] + kn, &As[cur ^ 1][ldsOff[i]]);
        LDSG(bS[i] + kn, &Bs[cur ^ 1][ldsOff[i]]);
      }
    }
    const char* Ab_ = (const char*)As[cur];
    const char* Bb_ = (const char*)Bs[cur];
#pragma unroll
    for (int kk = 0; kk < 2; ++kk) {
      int k0 = kk * 32 + (lane >> 4) * 8;
      bf16x8 af[4], bfr[4];
#pragma unroll
      for (int m = 0; m < 4; ++m) {
        int row = wr + m * 16 + (lane & 15);
        int boff = (row * 128 + k0 * 2) ^ ((row & 7) << 4);
        af[m] = *reinterpret_cast<const bf16x8*>(Ab_ + boff);
      }
#pragma unroll
      for (int n = 0; n < 4; ++n) {
        int row = wc + n * 16 + (lane & 15);
        int boff = (row * 128 + k0 * 2) ^ ((row & 7) << 4);
        bfr[n] = *reinterpret_cast<const bf16x8*>(Bb_ + boff);
      }
#pragma unroll
      for (int m = 0; m < 4; ++m)
#pragma unroll
        for (int n = 0; n < 4; ++n)
          acc[m][n] = __builtin_amdgcn_mfma_f32_16x16x32_bf16(af[m], bfr[n], acc[m][n], 0, 0, 0);
    }
    __syncthreads();
    cur ^= 1;
  }
  float* Cb = hvr + (long)mat * 262144;
#pragma unroll
  for (int n = 0; n < 4; ++n) {
    int col = n0 + wc + n * 16 + (lane & 15);
    float s = 0.f, q = 0.f;
#pragma unroll
    for (int m = 0; m < 4; ++m) {
      int row = m0 + wr + m * 16 + ((lane >> 4) << 2);
#pragma unroll
      for (int j = 0; j < 4; ++j) {
        float v = acc[m][n][j];
        s += v; q = fmaf(v, v, q);
        Cb[(long)(row + j) * 512 + col] = v;
      }
    }
    s += __shfl_xor(s, 16); s += __shfl_xor(s, 32);
    q += __shfl_xor(q, 16); q += __shfl_xor(q, 32);
    if (lane < 16) {
      csw[0][wave >> 1][wc + n * 16 + lane] = s;
      csw[1][wave >> 1][wc + n * 16 + lane] = q;
    }
  }
  __syncthreads();
  {
    int v = tid >> 7, cl = tid & 127;
    pstats[(((long)mat * 4 + mt) * 2 + v) * 512 + n0 + cl] =
        csw[v][0][cl] + csw[v][1][cl];
  }
}

// ---------------- finalize hx: bf16 C -> BN -> f32 out ----------------
__global__ __launch_bounds__(256) void k_finalize_hx(const short* __restrict__ Cbf,
                                                     const float* __restrict__ ss,
                                                     float* __restrict__ out) {
  long e = (long)blockIdx.x * 256 + threadIdx.x;   // 8-elem chunk
  long row = e >> 6;
  int c0 = (int)(e & 63) * 8;
  int mat = (int)(row >> 15);
  short8 h = *(const short8*)(Cbf + row * 512 + c0);
  const float* sb = ss + mat * 1024;
  f32x4 o0, o1;
#pragma unroll
  for (int j = 0; j < 4; ++j) o0[j] = fmaf(bf2f(h[j]), sb[c0 + j], sb[512 + c0 + j]);
#pragma unroll
  for (int j = 0; j < 4; ++j) o1[j] = fmaf(bf2f(h[4 + j]), sb[c0 + 4 + j], sb[512 + c0 + 4 + j]);
  *(f32x4*)(out + row * 512 + c0) = o0;
  *(f32x4*)(out + row * 512 + c0 + 4) = o1;
}

// ---------------- finalize hv: fused stat-reduce, BN, tile B=64, float4 stores ----------------
__global__ __launch_bounds__(256) void k_finalize_hv(const float* __restrict__ hvr,
                                                     const float* __restrict__ pstatsV,
                                                     const float* __restrict__ gv_g,
                                                     const float* __restrict__ gv_b,
                                                     float* __restrict__ outhv) {
  __shared__ float ssl[1024];
  int tp = blockIdx.x, tid = threadIdx.x;
  int mat = tp >> 9;
#pragma unroll
  for (int i = 0; i < 2; ++i) {
    int c = tid + i * 256;
    float s = 0.f, q = 0.f;
#pragma unroll
    for (int k = 0; k < 4; ++k) {
      s += pstatsV[(((long)mat * 4 + k) * 2 + 0) * 512 + c];
      q += pstatsV[(((long)mat * 4 + k) * 2 + 1) * 512 + c];
    }
    float mu = s * (1.f / 512.f);
    float var = fmaxf(q * (1.f / 512.f) - mu * mu, 0.f);
    float scale = rsqrtf(var + 1e-5f) * gv_g[mat * 512 + c];
    ssl[c] = scale;
    ssl[512 + c] = gv_b[mat * 512 + c] - mu * scale;
  }
  __syncthreads();
  int p = tp & 511;
  int c = (tid & 127) * 4;
  int bh = tid >> 7;
  f32x4 h = *(const f32x4*)(hvr + (long)tp * 512 + c);
  f32x4 o;
#pragma unroll
  for (int j = 0; j < 4; ++j) o[j] = fmaf(h[j], ssl[c + j], ssl[512 + c + j]);
  float* base = outhv + ((long)mat * 64 * 512 + p) * 512 + c;
#pragma unroll 4
  for (int k = 0; k < 32; ++k) {
    int b = bh + k * 2;
    *(f32x4*)(base + (long)b * 262144) = o;
  }
}

// ---------------- sim: 128x128 tiles, 8x8/thread, 4-way k-split, k-major LDS ----------------
__global__ __launch_bounds__(256) void k_sim(const float* __restrict__ vn,
                                             float* __restrict__ simP) {
  __shared__ float a[16][132];
  __shared__ float b[16][132];
  int tid = threadIdx.x;
  int tile = blockIdx.x >> 2, kh = blockIdx.x & 3;
  int i0 = (tile >> 3) * 128, j0 = (tile & 7) * 128;
  int row2 = tid >> 1, kg = (tid & 1) * 8;
  int tr = tid >> 4, tc = tid & 15;
  float acc[8][8] = {};
  for (int k0 = kh * 128; k0 < kh * 128 + 128; k0 += 16) {
    __syncthreads();
    f32x4 va0 = *(const f32x4*)(vn + (long)(i0 + row2) * 512 + k0 + kg);
    f32x4 va1 = *(const f32x4*)(vn + (long)(i0 + row2) * 512 + k0 + kg + 4);
    f32x4 vb0 = *(const f32x4*)(vn + (long)(j0 + row2) * 512 + k0 + kg);
    f32x4 vb1 = *(const f32x4*)(vn + (long)(j0 + row2) * 512 + k0 + kg + 4);
#pragma unroll
    for (int j = 0; j < 4; ++j) {
      a[kg + j][row2] = va0[j]; a[kg + 4 + j][row2] = va1[j];
      b[kg + j][row2] = vb0[j]; b[kg + 4 + j][row2] = vb1[j];
    }
    __syncthreads();
#pragma unroll
    for (int k = 0; k < 16; ++k) {
      f32x4 ar0 = *(const f32x4*)&a[k][tr * 8];
      f32x4 ar1 = *(const f32x4*)&a[k][tr * 8 + 4];
      f32x4 br0 = *(const f32x4*)&b[k][tc * 8];
      f32x4 br1 = *(const f32x4*)&b[k][tc * 8 + 4];
      float ar[8], br[8];
#pragma unroll
      for (int j = 0; j < 4; ++j) { ar[j] = ar0[j]; ar[4 + j] = ar1[j]; br[j] = br0[j]; br[4 + j] = br1[j]; }
#pragma unroll
      for (int i = 0; i < 8; ++i)
#pragma unroll
        for (int j = 0; j < 8; ++j)
          acc[i][j] = fmaf(ar[i], br[j], acc[i][j]);
    }
  }
  float* dst = simP + (long)kh * 1048576;
#pragma unroll
  for (int i = 0; i < 8; ++i) {
    f32x4 o0, o1;
#pragma unroll
    for (int j = 0; j < 4; ++j) { o0[j] = acc[i][j]; o1[j] = acc[i][4 + j]; }
    float* rowp = dst + (long)(i0 + tr * 8 + i) * 1024 + j0 + tc * 8;
    *(f32x4*)rowp = o0;
    *(f32x4*)(rowp + 4) = o1;
  }
}

// ---------------- top-30: one wave per row, registers + shfl butterfly ----------------
__global__ __launch_bounds__(256) void k_topk(const float* __restrict__ simP,
                                              float* __restrict__ outIdx) {
  int wv = threadIdx.x >> 6, lane = threadIdx.x & 63;
  int row = blockIdx.x * 4 + wv;
  const float* r0 = simP + (long)row * 1024;
  f32x4 v[4];
#pragma unroll
  for (int i = 0; i < 4; ++i) {
    f32x4 s = *(const f32x4*)(r0 + i * 256 + lane * 4);
#pragma unroll
    for (int h = 1; h < 4; ++h)
      s += *(const f32x4*)(r0 + (long)h * 1048576 + i * 256 + lane * 4);
    v[i] = s;
  }
  for (int it = 0; it < 30; ++it) {
    float bv = -1e30f; int bi = 1 << 30;
#pragma unroll
    for (int i = 0; i < 4; ++i)
#pragma unroll
      for (int j = 0; j < 4; ++j) {
        float val = v[i][j];
        if (val > bv) { bv = val; bi = i * 256 + lane * 4 + j; }
      }
#pragma unroll
    for (int off = 1; off < 64; off <<= 1) {
      float ov = __shfl_xor(bv, off);
      int oi = __shfl_xor(bi, off);
      if (ov > bv || (ov == bv && oi < bi)) { bv = ov; bi = oi; }
    }
    if (lane == 0) outIdx[(long)row * 30 + it] = (float)bi;
#pragma unroll
    for (int i = 0; i < 4; ++i)
#pragma unroll
      for (int j = 0; j < 4; ++j)
        if ((i * 256 + lane * 4 + j) == bi) v[i][j] = -1e30f;
  }
}

extern "C" void kernel_launch(void* const* d_in, const int* in_sizes, int n_in,
                              void* d_out, int out_size, void* d_ws, size_t ws_size,
                              hipStream_t stream) {
  (void)in_sizes; (void)n_in; (void)out_size; (void)ws_size;
  const float* x     = (const float*)d_in[0];
  const float* emb   = (const float*)d_in[1];
  const float* emb_g = (const float*)d_in[2];
  const float* emb_b = (const float*)d_in[3];
  const float* Wx    = (const float*)d_in[4];
  // d_in[5] = bx : cancels in BN
  const float* gx_g  = (const float*)d_in[6];
  const float* gx_b  = (const float*)d_in[7];
  const float* Wv    = (const float*)d_in[8];
  // d_in[9] = bv : cancels in BN
  const float* gv_g  = (const float*)d_in[10];
  const float* gv_b  = (const float*)d_in[11];
  float* out = (float*)d_out;

  char* ws = (char*)d_ws;
  short* hxr = (short*)ws;  ws += 65536L * 512 * 2;       // 67.1 MB
  short* Wxt = (short*)ws;  ws += 2L * 512 * 512 * 2;
  short* Wvt = (short*)ws;  ws += 2L * 512 * 512 * 2;
  short* vbf = (short*)ws;  ws += 1024L * 512 * 2;
  float* vn  = (float*)ws;  ws += 1024L * 512 * 4;
  float* hvr = (float*)ws;  ws += 2L * 512 * 512 * 4;
  float* simP = (float*)ws; ws += 4L * 1024 * 1024 * 4;   // 16 MB
  float* pstatsX = (float*)ws; ws += 2L * 256 * 2 * 512 * 4;
  float* pstatsE = (float*)ws; ws += 32L * 2 * 512 * 4;
  float* pstatsV = (float*)ws; ws += 2L * 4 * 2 * 512 * 4;
  float* ssE = (float*)ws;     ws += 2L * 512 * 4;
  float* ssX = (float*)ws;     ws += 4L * 512 * 4;

  k_transpose_w<<<dim3(8, 8, 4), 256, 0, stream>>>(Wx, Wv, Wxt, Wvt);
  k_colstats<<<32, 512, 0, stream>>>(emb, 32, pstatsE);
  k_colreduce<<<dim3(2, 1), 256, 0, stream>>>(pstatsE, 32, 1.f / 1024.f, emb_g, emb_b, 0, ssE);
  k_compute_v<<<1024, 256, 0, stream>>>(emb, ssE, vbf, vn);
  k_gemm_hx<<<2048, 256, 0, stream>>>(x, Wxt, hxr, pstatsX);
  k_colreduce<<<dim3(2, 2), 256, 0, stream>>>(pstatsX, 256, 1.f / 32768.f, gx_g, gx_b, 512, ssX);
  k_finalize_hx<<<16384, 256, 0, stream>>>(hxr, ssX, out);
  k_gemm_hv<<<32, 256, 0, stream>>>(vbf, Wvt, hvr, pstatsV);
  k_finalize_hv<<<1024, 256, 0, stream>>>(hvr, pstatsV, gv_g, gv_b, out + 65536L * 512);
  k_sim<<<256, 256, 0, stream>>>(vn, simP);
  k_topk<<<256, 256, 0, stream>>>(simP, out + 131072L * 512);
}

// Round 4
// 237.314 us; speedup vs baseline: 1.9316x; 1.3680x over previous
//
#include <hip/hip_runtime.h>
#include <hip/hip_bf16.h>
#include <cstdint>

// B=64, N=1024, L=512, D=512, T=2, P=512, K_top=30
// out: rows [0,65536) hx ; [65536,131072) hv tiled ; then 1024*30 topk idx (float)

typedef float f32x4 __attribute__((ext_vector_type(4)));
typedef __bf16 bf16x8 __attribute__((ext_vector_type(8)));
typedef short short8 __attribute__((ext_vector_type(8)));
typedef short short4v __attribute__((ext_vector_type(4)));

__device__ __forceinline__ short f2bf(float f) {
  union { float f; unsigned u; } x; x.f = f;
  unsigned r = x.u + 0x7fffu + ((x.u >> 16) & 1u);
  return (short)(r >> 16);
}
__device__ __forceinline__ float bf2f(short s) {
  union { unsigned u; float f; } x; x.u = ((unsigned)(unsigned short)s) << 16;
  return x.f;
}

#define LDSG(gp, lp) __builtin_amdgcn_global_load_lds(                     \
    (const __attribute__((address_space(1))) void*)(gp),                   \
    (__attribute__((address_space(3))) void*)(lp), 16, 0, 0)

// ---------------- prep: blocks [0,256) transpose W; [256,288) emb col-stats ----------------
__global__ __launch_bounds__(256) void k_prep(
    const float* __restrict__ Wx, const float* __restrict__ Wv,
    const float* __restrict__ emb,
    short* __restrict__ Wxt, short* __restrict__ Wvt,
    float* __restrict__ pstatsE) {
  __shared__ float t[64][65];
  int bid = blockIdx.x, tid = threadIdx.x;
  if (bid < 256) {
    int z = bid >> 6, tile = bid & 63;
    const float* W = (z < 2) ? (Wx + (long)z * 262144) : (Wv + (long)(z - 2) * 262144);
    short* Wt = (z < 2) ? (Wxt + (long)z * 262144) : (Wvt + (long)(z - 2) * 262144);
    int r0 = ((tile >> 3) & 7) * 64, c0 = (tile & 7) * 64;
    int lr = tid >> 4, lc = (tid & 15) * 4;
#pragma unroll
    for (int p = 0; p < 4; ++p) {
      f32x4 v = *(const f32x4*)(W + (long)(r0 + lr + p * 16) * 512 + c0 + lc);
#pragma unroll
      for (int j = 0; j < 4; ++j) t[lr + p * 16][lc + j] = v[j];
    }
    __syncthreads();
    int wr = (tid & 15) * 4;
    int wc = tid >> 4;
#pragma unroll
    for (int p = 0; p < 4; ++p) {
      int c = wc + p * 16;
      short4v o;
#pragma unroll
      for (int j = 0; j < 4; ++j) o[j] = f2bf(t[wr + j][c]);
      *(short4v*)(Wt + (long)(c0 + c) * 512 + r0 + wr) = o;
    }
  } else {
    int chunk = bid - 256;  // 32 chunks x 32 rows
    const float* p = emb + (long)chunk * 32 * 512;
#pragma unroll
    for (int i = 0; i < 2; ++i) {
      int c = tid + i * 256;
      float s = 0.f, q = 0.f;
#pragma unroll 4
      for (int r = 0; r < 32; ++r) {
        float v = p[(long)r * 512 + c];
        s += v; q = fmaf(v, v, q);
      }
      pstatsE[((long)chunk * 2 + 0) * 512 + c] = s;
      pstatsE[((long)chunk * 2 + 1) * 512 + c] = q;
    }
  }
}

// ---------------- reduce emb partials -> ssE ----------------
__global__ void k_colreduceE(const float* __restrict__ partial,
                             const float* __restrict__ gamma, const float* __restrict__ beta,
                             float* __restrict__ ss) {
  int c = blockIdx.x * 256 + threadIdx.x;
  float s = 0.f, q = 0.f;
  for (int k = 0; k < 32; ++k) {
    s += partial[((long)k * 2 + 0) * 512 + c];
    q += partial[((long)k * 2 + 1) * 512 + c];
  }
  float mu = s * (1.f / 1024.f);
  float var = fmaxf(q * (1.f / 1024.f) - mu * mu, 0.f);
  float scale = rsqrtf(var + 1e-5f) * gamma[c];
  ss[c] = scale;
  ss[512 + c] = beta[c] - mu * scale;
}

// ---------------- v = BN(emb) via ssE; vbf bf16; vn normalized ----------------
__global__ __launch_bounds__(256) void k_compute_v(const float* __restrict__ emb,
                                                   const float* __restrict__ ssE,
                                                   short* __restrict__ vbf,
                                                   float* __restrict__ vn) {
  __shared__ float red[256];
  int r = blockIdx.x, tid = threadIdx.x;
  float vals[2]; float sq = 0.f;
#pragma unroll
  for (int i = 0; i < 2; ++i) {
    int c = tid + i * 256;
    float xv = emb[(long)r * 512 + c];
    float val = fmaf(xv, ssE[c], ssE[512 + c]);
    vals[i] = val;
    sq = fmaf(val, val, sq);
    vbf[(long)r * 512 + c] = f2bf(val);
  }
  red[tid] = sq; __syncthreads();
  for (int s = 128; s > 0; s >>= 1) {
    if (tid < s) red[tid] += red[tid + s];
    __syncthreads();
  }
  float inv = 1.f / (sqrtf(red[0]) + 1e-8f);
#pragma unroll
  for (int i = 0; i < 2; ++i) {
    int c = tid + i * 256;
    vn[(long)r * 512 + c] = vals[i] * inv;
  }
}

// ---------------- fused GEMM: blocks [0,32) hv ; [32,2080) hx ----------------
__global__ __launch_bounds__(256, 2) void k_gemm(
    const float* __restrict__ x, const short* __restrict__ Wxt,
    const short* __restrict__ vbf, const short* __restrict__ Wvt,
    short* __restrict__ Cbf, float* __restrict__ hvr,
    float* __restrict__ pstatsX, float* __restrict__ pstatsV) {
  __shared__ short As[2][8192];
  __shared__ short Bs[2][8192];
  __shared__ float csw[2][2][128];
  int tid = threadIdx.x, lane = tid & 63, wave = tid >> 6;
  int wr = (wave >> 1) * 64, wc = (wave & 1) * 64;

  if (blockIdx.x < 32) {
    // ---- hv path ----
    int id = blockIdx.x;                  // mt*8 + nt*2 + mat
    int mt = id >> 3, nt = (id >> 1) & 3, mat = id & 1;
    int m0 = mt * 128, n0 = nt * 128;
    const short* Ab = vbf + ((long)mat * 512 + m0) * 512;
    const short* Bb = Wvt + (long)mat * 262144 + (long)n0 * 512;
    const short* aS[4]; const short* bS[4]; int ldsOff[4];
#pragma unroll
    for (int i = 0; i < 4; ++i) {
      int c = (wave * 4 + i) * 64 + lane;
      int row = c >> 3;
      int ccl = (c & 7) ^ (row & 7);
      aS[i] = Ab + (long)row * 512 + ccl * 8;
      bS[i] = Bb + (long)row * 512 + ccl * 8;
      ldsOff[i] = (wave * 4 + i) * 512;
    }
    f32x4 acc[4][4] = {};
#pragma unroll
    for (int i = 0; i < 4; ++i) { LDSG(aS[i], &As[0][ldsOff[i]]); LDSG(bS[i], &Bs[0][ldsOff[i]]); }
    __syncthreads();
    int cur = 0;
    for (int t = 0; t < 8; ++t) {
      int kn = (t + 1) * 64;
      if (t < 7) {
#pragma unroll
        for (int i = 0; i < 4; ++i) {
          LDSG(aS[i] + kn, &As[cur ^ 1][ldsOff[i]]);
          LDSG(bS[i] + kn, &Bs[cur ^ 1][ldsOff[i]]);
        }
      }
      const char* Ab_ = (const char*)As[cur];
      const char* Bb_ = (const char*)Bs[cur];
#pragma unroll
      for (int kk = 0; kk < 2; ++kk) {
        int k0 = kk * 32 + (lane >> 4) * 8;
        bf16x8 af[4], bfr[4];
#pragma unroll
        for (int m = 0; m < 4; ++m) {
          int row = wr + m * 16 + (lane & 15);
          int boff = (row * 128 + k0 * 2) ^ ((row & 7) << 4);
          af[m] = *reinterpret_cast<const bf16x8*>(Ab_ + boff);
        }
#pragma unroll
        for (int n = 0; n < 4; ++n) {
          int row = wc + n * 16 + (lane & 15);
          int boff = (row * 128 + k0 * 2) ^ ((row & 7) << 4);
          bfr[n] = *reinterpret_cast<const bf16x8*>(Bb_ + boff);
        }
#pragma unroll
        for (int m = 0; m < 4; ++m)
#pragma unroll
          for (int n = 0; n < 4; ++n)
            acc[m][n] = __builtin_amdgcn_mfma_f32_16x16x32_bf16(af[m], bfr[n], acc[m][n], 0, 0, 0);
      }
      __syncthreads();
      cur ^= 1;
    }
    float* Cb = hvr + (long)mat * 262144;
#pragma unroll
    for (int n = 0; n < 4; ++n) {
      int col = n0 + wc + n * 16 + (lane & 15);
      float s = 0.f, q = 0.f;
#pragma unroll
      for (int m = 0; m < 4; ++m) {
        int row = m0 + wr + m * 16 + ((lane >> 4) << 2);
#pragma unroll
        for (int j = 0; j < 4; ++j) {
          float v = acc[m][n][j];
          s += v; q = fmaf(v, v, q);
          Cb[(long)(row + j) * 512 + col] = v;
        }
      }
      s += __shfl_xor(s, 16); s += __shfl_xor(s, 32);
      q += __shfl_xor(q, 16); q += __shfl_xor(q, 32);
      if (lane < 16) {
        csw[0][wave >> 1][wc + n * 16 + lane] = s;
        csw[1][wave >> 1][wc + n * 16 + lane] = q;
      }
    }
    __syncthreads();
    {
      int v = tid >> 7, cl = tid & 127;
      pstatsV[(((long)mat * 4 + mt) * 2 + v) * 512 + n0 + cl] =
          csw[v][0][cl] + csw[v][1][cl];
    }
    return;
  }

  // ---- hx path ----
  int id = blockIdx.x - 32;
  int w = (id & 7) * 256 + (id >> 3);   // XCD-chunked
  int mt = w >> 3, rres = w & 7;
  int nt = rres & 3, mat = rres >> 2;
  int m0 = mt * 128, n0 = nt * 128;
  const short* Bb = Wxt + (long)mat * 262144 + (long)n0 * 512;

  const float* aSrc[4];
  int aOff[4];
#pragma unroll
  for (int i = 0; i < 4; ++i) {
    int c = i * 256 + tid;
    int row = c >> 3, g = c & 7;
    int rr = m0 + row;
    int b = rr >> 9, p = rr & 511;
    aSrc[i] = x + ((long)(b * 1024 + mat * 512 + p)) * 512 + g * 8;
    aOff[i] = (row * 128 + g * 16) ^ ((row & 7) << 4);
  }
  const short* bSrc[4];
  int ldsOff[4];
#pragma unroll
  for (int i = 0; i < 4; ++i) {
    int c = (wave * 4 + i) * 64 + lane;
    int row = c >> 3;
    int ccl = (c & 7) ^ (row & 7);
    bSrc[i] = Bb + (long)row * 512 + ccl * 8;
    ldsOff[i] = (wave * 4 + i) * 512;
  }
  f32x4 acc[4][4] = {};
  f32x4 a0[4], a1[4];

#pragma unroll
  for (int i = 0; i < 4; ++i) { a0[i] = *(const f32x4*)(aSrc[i]); a1[i] = *(const f32x4*)(aSrc[i] + 4); }
#pragma unroll
  for (int i = 0; i < 4; ++i) LDSG(bSrc[i], &Bs[0][ldsOff[i]]);
#pragma unroll
  for (int i = 0; i < 4; ++i) {
    short8 o;
#pragma unroll
    for (int j = 0; j < 4; ++j) { o[j] = f2bf(a0[i][j]); o[4 + j] = f2bf(a1[i][j]); }
    *(short8*)((char*)As[0] + aOff[i]) = o;
  }
  __syncthreads();

  int cur = 0;
  for (int t = 0; t < 8; ++t) {
    int kn = (t + 1) * 64;
    if (t < 7) {
#pragma unroll
      for (int i = 0; i < 4; ++i) {
        a0[i] = *(const f32x4*)(aSrc[i] + kn);
        a1[i] = *(const f32x4*)(aSrc[i] + kn + 4);
      }
#pragma unroll
      for (int i = 0; i < 4; ++i) LDSG(bSrc[i] + kn, &Bs[cur ^ 1][ldsOff[i]]);
    }
    const char* Ab_ = (const char*)As[cur];
    const char* Bb_ = (const char*)Bs[cur];
#pragma unroll
    for (int kk = 0; kk < 2; ++kk) {
      int k0 = kk * 32 + (lane >> 4) * 8;
      bf16x8 af[4], bfr[4];
#pragma unroll
      for (int m = 0; m < 4; ++m) {
        int row = wr + m * 16 + (lane & 15);
        int boff = (row * 128 + k0 * 2) ^ ((row & 7) << 4);
        af[m] = *reinterpret_cast<const bf16x8*>(Ab_ + boff);
      }
#pragma unroll
      for (int n = 0; n < 4; ++n) {
        int row = wc + n * 16 + (lane & 15);
        int boff = (row * 128 + k0 * 2) ^ ((row & 7) << 4);
        bfr[n] = *reinterpret_cast<const bf16x8*>(Bb_ + boff);
      }
#pragma unroll
      for (int m = 0; m < 4; ++m)
#pragma unroll
        for (int n = 0; n < 4; ++n)
          acc[m][n] = __builtin_amdgcn_mfma_f32_16x16x32_bf16(af[m], bfr[n], acc[m][n], 0, 0, 0);
    }
    if (t < 7) {
#pragma unroll
      for (int i = 0; i < 4; ++i) {
        short8 o;
#pragma unroll
        for (int j = 0; j < 4; ++j) { o[j] = f2bf(a0[i][j]); o[4 + j] = f2bf(a1[i][j]); }
        *(short8*)((char*)As[cur ^ 1] + aOff[i]) = o;
      }
    }
    __syncthreads();
    cur ^= 1;
  }
  short* Cb = Cbf + (long)mat * 32768 * 512;
#pragma unroll
  for (int n = 0; n < 4; ++n) {
    int col = n0 + wc + n * 16 + (lane & 15);
    float s = 0.f, q = 0.f;
#pragma unroll
    for (int m = 0; m < 4; ++m) {
      int row = m0 + wr + m * 16 + ((lane >> 4) << 2);
#pragma unroll
      for (int j = 0; j < 4; ++j) {
        float v = acc[m][n][j];
        s += v; q = fmaf(v, v, q);
        Cb[(long)(row + j) * 512 + col] = f2bf(v);
      }
    }
    s += __shfl_xor(s, 16); s += __shfl_xor(s, 32);
    q += __shfl_xor(q, 16); q += __shfl_xor(q, 32);
    if (lane < 16) {
      csw[0][wave >> 1][wc + n * 16 + lane] = s;
      csw[1][wave >> 1][wc + n * 16 + lane] = q;
    }
  }
  __syncthreads();
  {
    int v = tid >> 7, cl = tid & 127;
    pstatsX[(((long)mat * 256 + mt) * 2 + v) * 512 + n0 + cl] =
        csw[v][0][cl] + csw[v][1][cl];
  }
}

// ---------------- reduce X and V partials -> ssX, ssV ----------------
__global__ void k_colreduceXV(const float* __restrict__ pstatsX,
                              const float* __restrict__ pstatsV,
                              const float* __restrict__ gx_g, const float* __restrict__ gx_b,
                              const float* __restrict__ gv_g, const float* __restrict__ gv_b,
                              float* __restrict__ ssX, float* __restrict__ ssV) {
  int which = blockIdx.y;
  int c = blockIdx.x * 256 + threadIdx.x;
  if (which < 2) {
    int mat = which;
    float s = 0.f, q = 0.f;
    for (int k = 0; k < 256; ++k) {
      s += pstatsX[(((long)mat * 256 + k) * 2 + 0) * 512 + c];
      q += pstatsX[(((long)mat * 256 + k) * 2 + 1) * 512 + c];
    }
    float mu = s * (1.f / 32768.f);
    float var = fmaxf(q * (1.f / 32768.f) - mu * mu, 0.f);
    float scale = rsqrtf(var + 1e-5f) * gx_g[(long)mat * 512 + c];
    ssX[(mat * 2 + 0) * 512 + c] = scale;
    ssX[(mat * 2 + 1) * 512 + c] = gx_b[(long)mat * 512 + c] - mu * scale;
  } else {
    int mat = which - 2;
    float s = 0.f, q = 0.f;
    for (int k = 0; k < 4; ++k) {
      s += pstatsV[(((long)mat * 4 + k) * 2 + 0) * 512 + c];
      q += pstatsV[(((long)mat * 4 + k) * 2 + 1) * 512 + c];
    }
    float mu = s * (1.f / 512.f);
    float var = fmaxf(q * (1.f / 512.f) - mu * mu, 0.f);
    float scale = rsqrtf(var + 1e-5f) * gv_g[(long)mat * 512 + c];
    ssV[(mat * 2 + 0) * 512 + c] = scale;
    ssV[(mat * 2 + 1) * 512 + c] = gv_b[(long)mat * 512 + c] - mu * scale;
  }
}

// ---------------- fused finalize: [0,256) sim ; [256,384) hv-bcast ; rest hx ----------------
__global__ __launch_bounds__(256) void k_final(
    const short* __restrict__ Cbf, const float* __restrict__ ssX,
    const float* __restrict__ hvr, const float* __restrict__ ssV,
    const float* __restrict__ vn, float* __restrict__ simP,
    float* __restrict__ out) {
  __shared__ float a[16][132];
  __shared__ float b[16][132];
  int bid = blockIdx.x, tid = threadIdx.x;
  if (bid < 256) {
    // ---- sim: 128x128 tiles, 8x8/thread, 4-way k-split ----
    int tile = bid >> 2, kh = bid & 3;
    int i0 = (tile >> 3) * 128, j0 = (tile & 7) * 128;
    int row2 = tid >> 1, kg = (tid & 1) * 8;
    int tr = tid >> 4, tc = tid & 15;
    float acc[8][8] = {};
    for (int k0 = kh * 128; k0 < kh * 128 + 128; k0 += 16) {
      __syncthreads();
      f32x4 va0 = *(const f32x4*)(vn + (long)(i0 + row2) * 512 + k0 + kg);
      f32x4 va1 = *(const f32x4*)(vn + (long)(i0 + row2) * 512 + k0 + kg + 4);
      f32x4 vb0 = *(const f32x4*)(vn + (long)(j0 + row2) * 512 + k0 + kg);
      f32x4 vb1 = *(const f32x4*)(vn + (long)(j0 + row2) * 512 + k0 + kg + 4);
#pragma unroll
      for (int j = 0; j < 4; ++j) {
        a[kg + j][row2] = va0[j]; a[kg + 4 + j][row2] = va1[j];
        b[kg + j][row2] = vb0[j]; b[kg + 4 + j][row2] = vb1[j];
      }
      __syncthreads();
#pragma unroll
      for (int k = 0; k < 16; ++k) {
        f32x4 ar0 = *(const f32x4*)&a[k][tr * 8];
        f32x4 ar1 = *(const f32x4*)&a[k][tr * 8 + 4];
        f32x4 br0 = *(const f32x4*)&b[k][tc * 8];
        f32x4 br1 = *(const f32x4*)&b[k][tc * 8 + 4];
        float ar[8], br[8];
#pragma unroll
        for (int j = 0; j < 4; ++j) { ar[j] = ar0[j]; ar[4 + j] = ar1[j]; br[j] = br0[j]; br[4 + j] = br1[j]; }
#pragma unroll
        for (int i = 0; i < 8; ++i)
#pragma unroll
          for (int j = 0; j < 8; ++j)
            acc[i][j] = fmaf(ar[i], br[j], acc[i][j]);
      }
    }
    float* dst = simP + (long)kh * 1048576;
#pragma unroll
    for (int i = 0; i < 8; ++i) {
      f32x4 o0, o1;
#pragma unroll
      for (int j = 0; j < 4; ++j) { o0[j] = acc[i][j]; o1[j] = acc[i][4 + j]; }
      float* rowp = dst + (long)(i0 + tr * 8 + i) * 1024 + j0 + tc * 8;
      *(f32x4*)rowp = o0;
      *(f32x4*)(rowp + 4) = o1;
    }
  } else if (bid < 384) {
    // ---- hv broadcast: one block per (mat,b), contiguous 1 MB stream ----
    int b_ = bid - 256;
    int mat = b_ >> 6, bb = b_ & 63;
    int d = (tid & 127) * 4, pr = tid >> 7;
    f32x4 sc = *(const f32x4*)(ssV + ((long)mat * 2 + 0) * 512 + d);
    f32x4 sh = *(const f32x4*)(ssV + ((long)mat * 2 + 1) * 512 + d);
    const float* src = hvr + (long)mat * 262144;
    float* dst = out + 65536L * 512 + ((long)(mat * 64 + bb)) * 262144;
    for (int p0 = 0; p0 < 512; p0 += 2) {
      int p = p0 + pr;
      f32x4 h = *(const f32x4*)(src + (long)p * 512 + d);
      f32x4 o;
#pragma unroll
      for (int j = 0; j < 4; ++j) o[j] = fmaf(h[j], sc[j], sh[j]);
      *(f32x4*)(dst + (long)p * 512 + d) = o;
    }
  } else {
    // ---- hx finalize: bf16 -> BN -> f32 ----
    long e = (long)(bid - 384) * 256 + tid;   // 8-elem chunk
    long row = e >> 6;
    int c0 = (int)(e & 63) * 8;
    int mat = (int)(row >> 15);
    short8 h = *(const short8*)(Cbf + row * 512 + c0);
    const float* sb = ssX + mat * 1024;
    f32x4 o0, o1;
#pragma unroll
    for (int j = 0; j < 4; ++j) o0[j] = fmaf(bf2f(h[j]), sb[c0 + j], sb[512 + c0 + j]);
#pragma unroll
    for (int j = 0; j < 4; ++j) o1[j] = fmaf(bf2f(h[4 + j]), sb[c0 + 4 + j], sb[512 + c0 + 4 + j]);
    *(f32x4*)(out + row * 512 + c0) = o0;
    *(f32x4*)(out + row * 512 + c0 + 4) = o1;
  }
}

// ---------------- top-30: one wave per row, registers + shfl butterfly ----------------
__global__ __launch_bounds__(256) void k_topk(const float* __restrict__ simP,
                                              float* __restrict__ outIdx) {
  int wv = threadIdx.x >> 6, lane = threadIdx.x & 63;
  int row = blockIdx.x * 4 + wv;
  const float* r0 = simP + (long)row * 1024;
  f32x4 v[4];
#pragma unroll
  for (int i = 0; i < 4; ++i) {
    f32x4 s = *(const f32x4*)(r0 + i * 256 + lane * 4);
#pragma unroll
    for (int h = 1; h < 4; ++h)
      s += *(const f32x4*)(r0 + (long)h * 1048576 + i * 256 + lane * 4);
    v[i] = s;
  }
  for (int it = 0; it < 30; ++it) {
    float bv = -1e30f; int bi = 1 << 30;
#pragma unroll
    for (int i = 0; i < 4; ++i)
#pragma unroll
      for (int j = 0; j < 4; ++j) {
        float val = v[i][j];
        if (val > bv) { bv = val; bi = i * 256 + lane * 4 + j; }
      }
#pragma unroll
    for (int off = 1; off < 64; off <<= 1) {
      float ov = __shfl_xor(bv, off);
      int oi = __shfl_xor(bi, off);
      if (ov > bv || (ov == bv && oi < bi)) { bv = ov; bi = oi; }
    }
    if (lane == 0) outIdx[(long)row * 30 + it] = (float)bi;
#pragma unroll
    for (int i = 0; i < 4; ++i)
#pragma unroll
      for (int j = 0; j < 4; ++j)
        if ((i * 256 + lane * 4 + j) == bi) v[i][j] = -1e30f;
  }
}

extern "C" void kernel_launch(void* const* d_in, const int* in_sizes, int n_in,
                              void* d_out, int out_size, void* d_ws, size_t ws_size,
                              hipStream_t stream) {
  (void)in_sizes; (void)n_in; (void)out_size; (void)ws_size;
  const float* x     = (const float*)d_in[0];
  const float* emb   = (const float*)d_in[1];
  const float* emb_g = (const float*)d_in[2];
  const float* emb_b = (const float*)d_in[3];
  const float* Wx    = (const float*)d_in[4];
  // d_in[5] = bx : cancels in BN
  const float* gx_g  = (const float*)d_in[6];
  const float* gx_b  = (const float*)d_in[7];
  const float* Wv    = (const float*)d_in[8];
  // d_in[9] = bv : cancels in BN
  const float* gv_g  = (const float*)d_in[10];
  const float* gv_b  = (const float*)d_in[11];
  float* out = (float*)d_out;

  char* ws = (char*)d_ws;
  short* hxr = (short*)ws;  ws += 65536L * 512 * 2;       // 67.1 MB
  short* Wxt = (short*)ws;  ws += 2L * 512 * 512 * 2;
  short* Wvt = (short*)ws;  ws += 2L * 512 * 512 * 2;
  short* vbf = (short*)ws;  ws += 1024L * 512 * 2;
  float* vn  = (float*)ws;  ws += 1024L * 512 * 4;
  float* hvr = (float*)ws;  ws += 2L * 512 * 512 * 4;
  float* simP = (float*)ws; ws += 4L * 1024 * 1024 * 4;   // 16 MB
  float* pstatsX = (float*)ws; ws += 2L * 256 * 2 * 512 * 4;
  float* pstatsE = (float*)ws; ws += 32L * 2 * 512 * 4;
  float* pstatsV = (float*)ws; ws += 2L * 4 * 2 * 512 * 4;
  float* ssE = (float*)ws;     ws += 2L * 512 * 4;
  float* ssX = (float*)ws;     ws += 4L * 512 * 4;
  float* ssV = (float*)ws;     ws += 4L * 512 * 4;

  k_prep<<<288, 256, 0, stream>>>(Wx, Wv, emb, Wxt, Wvt, pstatsE);
  k_colreduceE<<<2, 256, 0, stream>>>(pstatsE, emb_g, emb_b, ssE);
  k_compute_v<<<1024, 256, 0, stream>>>(emb, ssE, vbf, vn);
  k_gemm<<<2080, 256, 0, stream>>>(x, Wxt, vbf, Wvt, hxr, hvr, pstatsX, pstatsV);
  k_colreduceXV<<<dim3(2, 4), 256, 0, stream>>>(pstatsX, pstatsV, gx_g, gx_b, gv_g, gv_b, ssX, ssV);
  k_final<<<16768, 256, 0, stream>>>(hxr, ssX, hvr, ssV, vn, simP, out);
  k_topk<<<256, 256, 0, stream>>>(simP, out + 131072L * 512);
}

// Round 6
// 226.355 us; speedup vs baseline: 2.0251x; 1.0484x over previous
//
#include <hip/hip_runtime.h>
#include <hip/hip_bf16.h>
#include <cstdint>

// B=64, N=1024, L=512, D=512, T=2, P=512, K_top=30
// out: rows [0,65536) hx ; [65536,131072) hv tiled ; then 1024*30 topk idx (float)

typedef float f32x4 __attribute__((ext_vector_type(4)));
typedef __bf16 bf16x8 __attribute__((ext_vector_type(8)));
typedef short short8 __attribute__((ext_vector_type(8)));
typedef short short4v __attribute__((ext_vector_type(4)));

__device__ __forceinline__ short f2bf(float f) {
  union { float f; unsigned u; } x; x.f = f;
  unsigned r = x.u + 0x7fffu + ((x.u >> 16) & 1u);
  return (short)(r >> 16);
}
__device__ __forceinline__ float bf2f(short s) {
  union { unsigned u; float f; } x; x.u = ((unsigned)(unsigned short)s) << 16;
  return x.f;
}

#define LDSG(gp, lp) __builtin_amdgcn_global_load_lds(                     \
    (const __attribute__((address_space(1))) void*)(gp),                   \
    (__attribute__((address_space(3))) void*)(lp), 16, 0, 0)

// ---------------- prep: [0,256) transpose W ; [256,272) emb col-stats ----------------
__global__ __launch_bounds__(256) void k_prep(
    const float* __restrict__ Wx, const float* __restrict__ Wv,
    const float* __restrict__ emb,
    short* __restrict__ Wxt, short* __restrict__ Wvt,
    float* __restrict__ pstatsE) {
  __shared__ float t[64][65];
  int bid = blockIdx.x, tid = threadIdx.x;
  if (bid < 256) {
    int z = bid >> 6, tile = bid & 63;
    const float* W = (z < 2) ? (Wx + (long)z * 262144) : (Wv + (long)(z - 2) * 262144);
    short* Wt = (z < 2) ? (Wxt + (long)z * 262144) : (Wvt + (long)(z - 2) * 262144);
    int r0 = (tile >> 3) * 64, c0 = (tile & 7) * 64;
    int lr = tid >> 4, lc = (tid & 15) * 4;
#pragma unroll
    for (int p = 0; p < 4; ++p) {
      f32x4 v = *(const f32x4*)(W + (long)(r0 + lr + p * 16) * 512 + c0 + lc);
#pragma unroll
      for (int j = 0; j < 4; ++j) t[lr + p * 16][lc + j] = v[j];
    }
    __syncthreads();
    int wr = (tid & 15) * 4;
    int wc = tid >> 4;
#pragma unroll
    for (int p = 0; p < 4; ++p) {
      int c = wc + p * 16;
      short4v o;
#pragma unroll
      for (int j = 0; j < 4; ++j) o[j] = f2bf(t[wr + j][c]);
      *(short4v*)(Wt + (long)(c0 + c) * 512 + r0 + wr) = o;
    }
  } else {
    int chunk = bid - 256;  // 16 chunks x 64 rows
    const float* p = emb + (long)chunk * 64 * 512;
#pragma unroll
    for (int i = 0; i < 2; ++i) {
      int c = tid + i * 256;
      float s = 0.f, q = 0.f;
#pragma unroll 4
      for (int r = 0; r < 64; ++r) {
        float v = p[(long)r * 512 + c];
        s += v; q = fmaf(v, v, q);
      }
      pstatsE[((long)chunk * 2 + 0) * 512 + c] = s;
      pstatsE[((long)chunk * 2 + 1) * 512 + c] = q;
    }
  }
}

// ---------------- v = BN(emb) (fused stat-reduce); vbf bf16; vn normalized ----------------
__global__ __launch_bounds__(256) void k_compute_v(const float* __restrict__ emb,
                                                   const float* __restrict__ pstatsE,
                                                   const float* __restrict__ gamma,
                                                   const float* __restrict__ beta,
                                                   short* __restrict__ vbf,
                                                   float* __restrict__ vn) {
  __shared__ float ssl[1024];
  __shared__ float red[256];
  int r = blockIdx.x, tid = threadIdx.x;
#pragma unroll
  for (int i = 0; i < 2; ++i) {
    int c = tid + i * 256;
    float s = 0.f, q = 0.f;
#pragma unroll
    for (int k = 0; k < 16; ++k) {
      s += pstatsE[((long)k * 2 + 0) * 512 + c];
      q += pstatsE[((long)k * 2 + 1) * 512 + c];
    }
    float mu = s * (1.f / 1024.f);
    float var = fmaxf(q * (1.f / 1024.f) - mu * mu, 0.f);
    float scale = rsqrtf(var + 1e-5f) * gamma[c];
    ssl[c] = scale;
    ssl[512 + c] = beta[c] - mu * scale;
  }
  __syncthreads();
  float vals[2]; float sq = 0.f;
#pragma unroll
  for (int i = 0; i < 2; ++i) {
    int c = tid + i * 256;
    float xv = emb[(long)r * 512 + c];
    float val = fmaf(xv, ssl[c], ssl[512 + c]);
    vals[i] = val;
    sq = fmaf(val, val, sq);
    vbf[(long)r * 512 + c] = f2bf(val);
  }
  red[tid] = sq; __syncthreads();
  for (int s = 128; s > 0; s >>= 1) {
    if (tid < s) red[tid] += red[tid + s];
    __syncthreads();
  }
  float inv = 1.f / (sqrtf(red[0]) + 1e-8f);
#pragma unroll
  for (int i = 0; i < 2; ++i) {
    int c = tid + i * 256;
    vn[(long)r * 512 + c] = vals[i] * inv;
  }
}

// ---------------- fused GEMM+sim: [0,32) hv ; [32,288) sim ; [288,2336) hx ----------------
// LDS layout (67584 B): [0,16384) As buf0 | [16384,32768) As buf1
//                       [32768,49152) Bs buf0 | [49152,65536) Bs buf1 | [65536,67584) csw
// sim branch aliases: a[16][132] at 0, b[16][132] at 8448.
#define ASP(b) ((short*)(smem + ((b) << 14)))
#define BSP(b) ((short*)(smem + 32768 + ((b) << 14)))
#define CSW    ((float(*)[2][128])(smem + 65536))
#define SIMA   ((float(*)[132])(smem))
#define SIMB   ((float(*)[132])(smem + 8448))

__global__ __launch_bounds__(256, 2) void k_gemm(
    const float* __restrict__ x, const short* __restrict__ Wxt,
    const short* __restrict__ vbf, const short* __restrict__ Wvt,
    const float* __restrict__ vn,
    short* __restrict__ Cbf, float* __restrict__ hvr, float* __restrict__ simP,
    float* __restrict__ pstatsX, float* __restrict__ pstatsV) {
  __shared__ char smem[67584];
  int tid = threadIdx.x, lane = tid & 63, wave = tid >> 6;
  int wr = (wave >> 1) * 64, wc = (wave & 1) * 64;

  if (blockIdx.x >= 32 && blockIdx.x < 288) {
    // ---- sim: 128x128 tiles, 8x8/thread, 4-way k-split, k-major LDS ----
    int sid = blockIdx.x - 32;
    int tile = sid >> 2, kh = sid & 3;
    int i0 = (tile >> 3) * 128, j0 = (tile & 7) * 128;
    int row2 = tid >> 1, kg = (tid & 1) * 8;
    int tr = tid >> 4, tc = tid & 15;
    float acc[8][8] = {};
    for (int k0 = kh * 128; k0 < kh * 128 + 128; k0 += 16) {
      __syncthreads();
      f32x4 va0 = *(const f32x4*)(vn + (long)(i0 + row2) * 512 + k0 + kg);
      f32x4 va1 = *(const f32x4*)(vn + (long)(i0 + row2) * 512 + k0 + kg + 4);
      f32x4 vb0 = *(const f32x4*)(vn + (long)(j0 + row2) * 512 + k0 + kg);
      f32x4 vb1 = *(const f32x4*)(vn + (long)(j0 + row2) * 512 + k0 + kg + 4);
#pragma unroll
      for (int j = 0; j < 4; ++j) {
        SIMA[kg + j][row2] = va0[j]; SIMA[kg + 4 + j][row2] = va1[j];
        SIMB[kg + j][row2] = vb0[j]; SIMB[kg + 4 + j][row2] = vb1[j];
      }
      __syncthreads();
#pragma unroll
      for (int k = 0; k < 16; ++k) {
        f32x4 ar0 = *(const f32x4*)&SIMA[k][tr * 8];
        f32x4 ar1 = *(const f32x4*)&SIMA[k][tr * 8 + 4];
        f32x4 br0 = *(const f32x4*)&SIMB[k][tc * 8];
        f32x4 br1 = *(const f32x4*)&SIMB[k][tc * 8 + 4];
        float ar[8], br[8];
#pragma unroll
        for (int j = 0; j < 4; ++j) { ar[j] = ar0[j]; ar[4 + j] = ar1[j]; br[j] = br0[j]; br[4 + j] = br1[j]; }
#pragma unroll
        for (int i = 0; i < 8; ++i)
#pragma unroll
          for (int j = 0; j < 8; ++j)
            acc[i][j] = fmaf(ar[i], br[j], acc[i][j]);
      }
    }
    float* dst = simP + (long)kh * 1048576;
#pragma unroll
    for (int i = 0; i < 8; ++i) {
      f32x4 o0, o1;
#pragma unroll
      for (int j = 0; j < 4; ++j) { o0[j] = acc[i][j]; o1[j] = acc[i][4 + j]; }
      float* rowp = dst + (long)(i0 + tr * 8 + i) * 1024 + j0 + tc * 8;
      *(f32x4*)rowp = o0;
      *(f32x4*)(rowp + 4) = o1;
    }
    return;
  }

  if (blockIdx.x < 32) {
    // ---- hv path ----
    int id = blockIdx.x;                  // mt*8 + nt*2 + mat
    int mt = id >> 3, nt = (id >> 1) & 3, mat = id & 1;
    int m0 = mt * 128, n0 = nt * 128;
    const short* Ab = vbf + ((long)mat * 512 + m0) * 512;
    const short* Bb = Wvt + (long)mat * 262144 + (long)n0 * 512;
    const short* aS[4]; const short* bS[4]; int ldsOff[4];
#pragma unroll
    for (int i = 0; i < 4; ++i) {
      int c = (wave * 4 + i) * 64 + lane;
      int row = c >> 3;
      int ccl = (c & 7) ^ (row & 7);
      aS[i] = Ab + (long)row * 512 + ccl * 8;
      bS[i] = Bb + (long)row * 512 + ccl * 8;
      ldsOff[i] = (wave * 4 + i) * 512;
    }
    f32x4 acc[4][4] = {};
#pragma unroll
    for (int i = 0; i < 4; ++i) { LDSG(aS[i], ASP(0) + ldsOff[i]); LDSG(bS[i], BSP(0) + ldsOff[i]); }
    __syncthreads();
    int cur = 0;
    for (int t = 0; t < 8; ++t) {
      int kn = (t + 1) * 64;
      if (t < 7) {
#pragma unroll
        for (int i = 0; i < 4; ++i) {
          LDSG(aS[i] + kn, ASP(cur ^ 1) + ldsOff[i]);
          LDSG(bS[i] + kn, BSP(cur ^ 1) + ldsOff[i]);
        }
      }
      const char* Ab_ = (const char*)ASP(cur);
      const char* Bb_ = (const char*)BSP(cur);
#pragma unroll
      for (int kk = 0; kk < 2; ++kk) {
        int k0 = kk * 32 + (lane >> 4) * 8;
        bf16x8 af[4], bfr[4];
#pragma unroll
        for (int m = 0; m < 4; ++m) {
          int row = wr + m * 16 + (lane & 15);
          int boff = (row * 128 + k0 * 2) ^ ((row & 7) << 4);
          af[m] = *reinterpret_cast<const bf16x8*>(Ab_ + boff);
        }
#pragma unroll
        for (int n = 0; n < 4; ++n) {
          int row = wc + n * 16 + (lane & 15);
          int boff = (row * 128 + k0 * 2) ^ ((row & 7) << 4);
          bfr[n] = *reinterpret_cast<const bf16x8*>(Bb_ + boff);
        }
#pragma unroll
        for (int m = 0; m < 4; ++m)
#pragma unroll
          for (int n = 0; n < 4; ++n)
            acc[m][n] = __builtin_amdgcn_mfma_f32_16x16x32_bf16(af[m], bfr[n], acc[m][n], 0, 0, 0);
      }
      __syncthreads();
      cur ^= 1;
    }
    float* Cb = hvr + (long)mat * 262144;
#pragma unroll
    for (int n = 0; n < 4; ++n) {
      int col = n0 + wc + n * 16 + (lane & 15);
      float s = 0.f, q = 0.f;
#pragma unroll
      for (int m = 0; m < 4; ++m) {
        int row = m0 + wr + m * 16 + ((lane >> 4) << 2);
#pragma unroll
        for (int j = 0; j < 4; ++j) {
          float v = acc[m][n][j];
          s += v; q = fmaf(v, v, q);
          Cb[(long)(row + j) * 512 + col] = v;
        }
      }
      s += __shfl_xor(s, 16); s += __shfl_xor(s, 32);
      q += __shfl_xor(q, 16); q += __shfl_xor(q, 32);
      if (lane < 16) {
        CSW[0][wave >> 1][wc + n * 16 + lane] = s;
        CSW[1][wave >> 1][wc + n * 16 + lane] = q;
      }
    }
    __syncthreads();
    {
      int v = tid >> 7, cl = tid & 127;
      pstatsV[(((long)mat * 4 + mt) * 2 + v) * 512 + n0 + cl] =
          CSW[v][0][cl] + CSW[v][1][cl];
    }
    return;
  }

  // ---- hx path ----
  int id = blockIdx.x - 288;
  int w = (id & 7) * 256 + (id >> 3);   // XCD-chunked
  int mt = w >> 3, rres = w & 7;
  int nt = rres & 3, mat = rres >> 2;
  int m0 = mt * 128, n0 = nt * 128;
  const short* Bb = Wxt + (long)mat * 262144 + (long)n0 * 512;

  const float* aSrc[4];
  int aOff[4];
#pragma unroll
  for (int i = 0; i < 4; ++i) {
    int c = i * 256 + tid;
    int row = c >> 3, g = c & 7;
    int rr = m0 + row;
    int b = rr >> 9, p = rr & 511;
    aSrc[i] = x + ((long)(b * 1024 + mat * 512 + p)) * 512 + g * 8;
    aOff[i] = (row * 128 + g * 16) ^ ((row & 7) << 4);
  }
  const short* bSrc[4];
  int ldsOff[4];
#pragma unroll
  for (int i = 0; i < 4; ++i) {
    int c = (wave * 4 + i) * 64 + lane;
    int row = c >> 3;
    int ccl = (c & 7) ^ (row & 7);
    bSrc[i] = Bb + (long)row * 512 + ccl * 8;
    ldsOff[i] = (wave * 4 + i) * 512;
  }
  f32x4 acc[4][4] = {};
  f32x4 a0[4], a1[4];

#pragma unroll
  for (int i = 0; i < 4; ++i) { a0[i] = *(const f32x4*)(aSrc[i]); a1[i] = *(const f32x4*)(aSrc[i] + 4); }
#pragma unroll
  for (int i = 0; i < 4; ++i) LDSG(bSrc[i], BSP(0) + ldsOff[i]);
#pragma unroll
  for (int i = 0; i < 4; ++i) {
    short8 o;
#pragma unroll
    for (int j = 0; j < 4; ++j) { o[j] = f2bf(a0[i][j]); o[4 + j] = f2bf(a1[i][j]); }
    *(short8*)((char*)ASP(0) + aOff[i]) = o;
  }
  __syncthreads();

  int cur = 0;
  for (int t = 0; t < 8; ++t) {
    int kn = (t + 1) * 64;
    if (t < 7) {
#pragma unroll
      for (int i = 0; i < 4; ++i) {
        a0[i] = *(const f32x4*)(aSrc[i] + kn);
        a1[i] = *(const f32x4*)(aSrc[i] + kn + 4);
      }
#pragma unroll
      for (int i = 0; i < 4; ++i) LDSG(bSrc[i] + kn, BSP(cur ^ 1) + ldsOff[i]);
    }
    const char* Ab_ = (const char*)ASP(cur);
    const char* Bb_ = (const char*)BSP(cur);
#pragma unroll
    for (int kk = 0; kk < 2; ++kk) {
      int k0 = kk * 32 + (lane >> 4) * 8;
      bf16x8 af[4], bfr[4];
#pragma unroll
      for (int m = 0; m < 4; ++m) {
        int row = wr + m * 16 + (lane & 15);
        int boff = (row * 128 + k0 * 2) ^ ((row & 7) << 4);
        af[m] = *reinterpret_cast<const bf16x8*>(Ab_ + boff);
      }
#pragma unroll
      for (int n = 0; n < 4; ++n) {
        int row = wc + n * 16 + (lane & 15);
        int boff = (row * 128 + k0 * 2) ^ ((row & 7) << 4);
        bfr[n] = *reinterpret_cast<const bf16x8*>(Bb_ + boff);
      }
#pragma unroll
      for (int m = 0; m < 4; ++m)
#pragma unroll
        for (int n = 0; n < 4; ++n)
          acc[m][n] = __builtin_amdgcn_mfma_f32_16x16x32_bf16(af[m], bfr[n], acc[m][n], 0, 0, 0);
    }
    if (t < 7) {
#pragma unroll
      for (int i = 0; i < 4; ++i) {
        short8 o;
#pragma unroll
        for (int j = 0; j < 4; ++j) { o[j] = f2bf(a0[i][j]); o[4 + j] = f2bf(a1[i][j]); }
        *(short8*)((char*)ASP(cur ^ 1) + aOff[i]) = o;
      }
    }
    __syncthreads();
    cur ^= 1;
  }
  short* Cb = Cbf + (long)mat * 32768 * 512;
#pragma unroll
  for (int n = 0; n < 4; ++n) {
    int col = n0 + wc + n * 16 + (lane & 15);
    float s = 0.f, q = 0.f;
#pragma unroll
    for (int m = 0; m < 4; ++m) {
      int row = m0 + wr + m * 16 + ((lane >> 4) << 2);
#pragma unroll
      for (int j = 0; j < 4; ++j) {
        float v = acc[m][n][j];
        s += v; q = fmaf(v, v, q);
        Cb[(long)(row + j) * 512 + col] = f2bf(v);
      }
    }
    s += __shfl_xor(s, 16); s += __shfl_xor(s, 32);
    q += __shfl_xor(q, 16); q += __shfl_xor(q, 32);
    if (lane < 16) {
      CSW[0][wave >> 1][wc + n * 16 + lane] = s;
      CSW[1][wave >> 1][wc + n * 16 + lane] = q;
    }
  }
  __syncthreads();
  {
    int v = tid >> 7, cl = tid & 127;
    pstatsX[(((long)mat * 256 + mt) * 2 + v) * 512 + n0 + cl] =
        CSW[v][0][cl] + CSW[v][1][cl];
  }
}

// ---------------- reduce X and V partials -> ssX, ssV ----------------
__global__ void k_colreduceXV(const float* __restrict__ pstatsX,
                              const float* __restrict__ pstatsV,
                              const float* __restrict__ gx_g, const float* __restrict__ gx_b,
                              const float* __restrict__ gv_g, const float* __restrict__ gv_b,
                              float* __restrict__ ssX, float* __restrict__ ssV) {
  int which = blockIdx.y;
  int c = blockIdx.x * 256 + threadIdx.x;
  if (which < 2) {
    int mat = which;
    float s = 0.f, q = 0.f;
    for (int k = 0; k < 256; ++k) {
      s += pstatsX[(((long)mat * 256 + k) * 2 + 0) * 512 + c];
      q += pstatsX[(((long)mat * 256 + k) * 2 + 1) * 512 + c];
    }
    float mu = s * (1.f / 32768.f);
    float var = fmaxf(q * (1.f / 32768.f) - mu * mu, 0.f);
    float scale = rsqrtf(var + 1e-5f) * gx_g[(long)mat * 512 + c];
    ssX[(mat * 2 + 0) * 512 + c] = scale;
    ssX[(mat * 2 + 1) * 512 + c] = gx_b[(long)mat * 512 + c] - mu * scale;
  } else {
    int mat = which - 2;
    float s = 0.f, q = 0.f;
    for (int k = 0; k < 4; ++k) {
      s += pstatsV[(((long)mat * 4 + k) * 2 + 0) * 512 + c];
      q += pstatsV[(((long)mat * 4 + k) * 2 + 1) * 512 + c];
    }
    float mu = s * (1.f / 512.f);
    float var = fmaxf(q * (1.f / 512.f) - mu * mu, 0.f);
    float scale = rsqrtf(var + 1e-5f) * gv_g[(long)mat * 512 + c];
    ssV[(mat * 2 + 0) * 512 + c] = scale;
    ssV[(mat * 2 + 1) * 512 + c] = gv_b[(long)mat * 512 + c] - mu * scale;
  }
}

// ---------------- fused finalize: [0,256) topk ; [256,384) hv-bcast ; rest hx ----------------
__global__ __launch_bounds__(256) void k_final(
    const short* __restrict__ Cbf, const float* __restrict__ ssX,
    const float* __restrict__ hvr, const float* __restrict__ ssV,
    const float* __restrict__ simP, float* __restrict__ out) {
  int bid = blockIdx.x, tid = threadIdx.x;
  if (bid < 256) {
    // ---- topk: one wave per row ----
    int wv = tid >> 6, lane = tid & 63;
    int row = bid * 4 + wv;
    const float* r0 = simP + (long)row * 1024;
    f32x4 v[4];
#pragma unroll
    for (int i = 0; i < 4; ++i) {
      f32x4 s = *(const f32x4*)(r0 + i * 256 + lane * 4);
#pragma unroll
      for (int h = 1; h < 4; ++h)
        s += *(const f32x4*)(r0 + (long)h * 1048576 + i * 256 + lane * 4);
      v[i] = s;
    }
    float* outIdx = out + 131072L * 512;
    for (int it = 0; it < 30; ++it) {
      float bv = -1e30f; int bi = 1 << 30;
#pragma unroll
      for (int i = 0; i < 4; ++i)
#pragma unroll
        for (int j = 0; j < 4; ++j) {
          float val = v[i][j];
          if (val > bv) { bv = val; bi = i * 256 + lane * 4 + j; }
        }
#pragma unroll
      for (int off = 1; off < 64; off <<= 1) {
        float ov = __shfl_xor(bv, off);
        int oi = __shfl_xor(bi, off);
        if (ov > bv || (ov == bv && oi < bi)) { bv = ov; bi = oi; }
      }
      if (lane == 0) outIdx[(long)row * 30 + it] = (float)bi;
#pragma unroll
      for (int i = 0; i < 4; ++i)
#pragma unroll
        for (int j = 0; j < 4; ++j)
          if ((i * 256 + lane * 4 + j) == bi) v[i][j] = -1e30f;
    }
  } else if (bid < 384) {
    // ---- hv broadcast: one block per (mat,b), contiguous 1 MB stream ----
    int b_ = bid - 256;
    int mat = b_ >> 6, bb = b_ & 63;
    int d = (tid & 127) * 4, pr = tid >> 7;
    f32x4 sc = *(const f32x4*)(ssV + ((long)mat * 2 + 0) * 512 + d);
    f32x4 sh = *(const f32x4*)(ssV + ((long)mat * 2 + 1) * 512 + d);
    const float* src = hvr + (long)mat * 262144;
    float* dst = out + 65536L * 512 + ((long)(mat * 64 + bb)) * 262144;
    for (int p0 = 0; p0 < 512; p0 += 2) {
      int p = p0 + pr;
      f32x4 h = *(const f32x4*)(src + (long)p * 512 + d);
      f32x4 o;
#pragma unroll
      for (int j = 0; j < 4; ++j) o[j] = fmaf(h[j], sc[j], sh[j]);
      *(f32x4*)(dst + (long)p * 512 + d) = o;
    }
  } else {
    // ---- hx finalize: bf16 -> BN -> f32 ----
    long e = (long)(bid - 384) * 256 + tid;   // 8-elem chunk
    long row = e >> 6;
    int c0 = (int)(e & 63) * 8;
    int mat = (int)(row >> 15);
    short8 h = *(const short8*)(Cbf + row * 512 + c0);
    const float* sb = ssX + mat * 1024;
    f32x4 o0, o1;
#pragma unroll
    for (int j = 0; j < 4; ++j) o0[j] = fmaf(bf2f(h[j]), sb[c0 + j], sb[512 + c0 + j]);
#pragma unroll
    for (int j = 0; j < 4; ++j) o1[j] = fmaf(bf2f(h[4 + j]), sb[c0 + 4 + j], sb[512 + c0 + 4 + j]);
    *(f32x4*)(out + row * 512 + c0) = o0;
    *(f32x4*)(out + row * 512 + c0 + 4) = o1;
  }
}

extern "C" void kernel_launch(void* const* d_in, const int* in_sizes, int n_in,
                              void* d_out, int out_size, void* d_ws, size_t ws_size,
                              hipStream_t stream) {
  (void)in_sizes; (void)n_in; (void)out_size; (void)ws_size;
  const float* x     = (const float*)d_in[0];
  const float* emb   = (const float*)d_in[1];
  const float* emb_g = (const float*)d_in[2];
  const float* emb_b = (const float*)d_in[3];
  const float* Wx    = (const float*)d_in[4];
  // d_in[5] = bx : cancels in BN
  const float* gx_g  = (const float*)d_in[6];
  const float* gx_b  = (const float*)d_in[7];
  const float* Wv    = (const float*)d_in[8];
  // d_in[9] = bv : cancels in BN
  const float* gv_g  = (const float*)d_in[10];
  const float* gv_b  = (const float*)d_in[11];
  float* out = (float*)d_out;

  char* ws = (char*)d_ws;
  short* hxr = (short*)ws;  ws += 65536L * 512 * 2;       // 67.1 MB
  short* Wxt = (short*)ws;  ws += 2L * 512 * 512 * 2;
  short* Wvt = (short*)ws;  ws += 2L * 512 * 512 * 2;
  short* vbf = (short*)ws;  ws += 1024L * 512 * 2;
  float* vn  = (float*)ws;  ws += 1024L * 512 * 4;
  float* hvr = (float*)ws;  ws += 2L * 512 * 512 * 4;
  float* simP = (float*)ws; ws += 4L * 1024 * 1024 * 4;   // 16 MB
  float* pstatsX = (float*)ws; ws += 2L * 256 * 2 * 512 * 4;
  float* pstatsE = (float*)ws; ws += 16L * 2 * 512 * 4;
  float* pstatsV = (float*)ws; ws += 2L * 4 * 2 * 512 * 4;
  float* ssX = (float*)ws;     ws += 4L * 512 * 4;
  float* ssV = (float*)ws;     ws += 4L * 512 * 4;

  k_prep<<<272, 256, 0, stream>>>(Wx, Wv, emb, Wxt, Wvt, pstatsE);
  k_compute_v<<<1024, 256, 0, stream>>>(emb, pstatsE, emb_g, emb_b, vbf, vn);
  k_gemm<<<2336, 256, 0, stream>>>(x, Wxt, vbf, Wvt, vn, hxr, hvr, simP, pstatsX, pstatsV);
  k_colreduceXV<<<dim3(2, 4), 256, 0, stream>>>(pstatsX, pstatsV, gx_g, gx_b, gv_g, gv_b, ssX, ssV);
  k_final<<<16768, 256, 0, stream>>>(hxr, ssX, hvr, ssV, simP, out);
}

// Round 7
// 209.405 us; speedup vs baseline: 2.1890x; 1.0809x over previous
//
#include <hip/hip_runtime.h>
#include <hip/hip_bf16.h>
#include <cstdint>

// B=64, N=1024, L=512, D=512, T=2, P=512, K_top=30
// out: rows [0,65536) hx ; [65536,131072) hv tiled ; then 1024*30 topk idx (float)

typedef float f32x4 __attribute__((ext_vector_type(4)));
typedef __bf16 bf16x8 __attribute__((ext_vector_type(8)));
typedef short short8 __attribute__((ext_vector_type(8)));
typedef short short4v __attribute__((ext_vector_type(4)));

__device__ __forceinline__ short f2bf(float f) {
  __hip_bfloat16 h = __float2bfloat16(f);   // native cvt (RNE), compiles to v_cvt_pk_bf16_f32
  return *reinterpret_cast<short*>(&h);
}
__device__ __forceinline__ float bf2f(short s) {
  union { unsigned u; float f; } x; x.u = ((unsigned)(unsigned short)s) << 16;
  return x.f;
}

#define LDSG(gp, lp) __builtin_amdgcn_global_load_lds(                     \
    (const __attribute__((address_space(1))) void*)(gp),                   \
    (__attribute__((address_space(3))) void*)(lp), 16, 0, 0)

// ---------------- prep: [0,256) transpose W ; [256,272) emb col-stats ----------------
__global__ __launch_bounds__(256) void k_prep(
    const float* __restrict__ Wx, const float* __restrict__ Wv,
    const float* __restrict__ emb,
    short* __restrict__ Wxt, short* __restrict__ Wvt,
    float* __restrict__ pstatsE) {
  __shared__ float t[64][65];
  int bid = blockIdx.x, tid = threadIdx.x;
  if (bid < 256) {
    int z = bid >> 6, tile = bid & 63;
    const float* W = (z < 2) ? (Wx + (long)z * 262144) : (Wv + (long)(z - 2) * 262144);
    short* Wt = (z < 2) ? (Wxt + (long)z * 262144) : (Wvt + (long)(z - 2) * 262144);
    int r0 = (tile >> 3) * 64, c0 = (tile & 7) * 64;
    int lr = tid >> 4, lc = (tid & 15) * 4;
#pragma unroll
    for (int p = 0; p < 4; ++p) {
      f32x4 v = *(const f32x4*)(W + (long)(r0 + lr + p * 16) * 512 + c0 + lc);
#pragma unroll
      for (int j = 0; j < 4; ++j) t[lr + p * 16][lc + j] = v[j];
    }
    __syncthreads();
    int wr = (tid & 15) * 4;
    int wc = tid >> 4;
#pragma unroll
    for (int p = 0; p < 4; ++p) {
      int c = wc + p * 16;
      short4v o;
#pragma unroll
      for (int j = 0; j < 4; ++j) o[j] = f2bf(t[wr + j][c]);
      *(short4v*)(Wt + (long)(c0 + c) * 512 + r0 + wr) = o;
    }
  } else {
    int chunk = bid - 256;  // 16 chunks x 64 rows
    const float* p = emb + (long)chunk * 64 * 512;
#pragma unroll
    for (int i = 0; i < 2; ++i) {
      int c = tid + i * 256;
      float s = 0.f, q = 0.f;
#pragma unroll 4
      for (int r = 0; r < 64; ++r) {
        float v = p[(long)r * 512 + c];
        s += v; q = fmaf(v, v, q);
      }
      pstatsE[((long)chunk * 2 + 0) * 512 + c] = s;
      pstatsE[((long)chunk * 2 + 1) * 512 + c] = q;
    }
  }
}

// ---------------- v = BN(emb): wave-per-row; vbf bf16; vn normalized ----------------
__global__ __launch_bounds__(256) void k_compute_v(const float* __restrict__ emb,
                                                   const float* __restrict__ pstatsE,
                                                   const float* __restrict__ gamma,
                                                   const float* __restrict__ beta,
                                                   short* __restrict__ vbf,
                                                   float* __restrict__ vn) {
  __shared__ float ssl[1024];
  int tid = threadIdx.x, wv = tid >> 6, lane = tid & 63;
#pragma unroll
  for (int i = 0; i < 2; ++i) {
    int c = tid + i * 256;
    float s = 0.f, q = 0.f;
#pragma unroll
    for (int k = 0; k < 16; ++k) {
      s += pstatsE[((long)k * 2 + 0) * 512 + c];
      q += pstatsE[((long)k * 2 + 1) * 512 + c];
    }
    float mu = s * (1.f / 1024.f);
    float var = fmaxf(q * (1.f / 1024.f) - mu * mu, 0.f);
    float scale = rsqrtf(var + 1e-5f) * gamma[c];
    ssl[c] = scale;
    ssl[512 + c] = beta[c] - mu * scale;
  }
  __syncthreads();
  int r = blockIdx.x * 4 + wv;
  const float* src = emb + (long)r * 512 + lane * 8;
  f32x4 x0 = *(const f32x4*)src;
  f32x4 x1 = *(const f32x4*)(src + 4);
  float vals[8]; float sq = 0.f;
  int c0 = lane * 8;
#pragma unroll
  for (int j = 0; j < 4; ++j) {
    vals[j] = fmaf(x0[j], ssl[c0 + j], ssl[512 + c0 + j]);
    vals[4 + j] = fmaf(x1[j], ssl[c0 + 4 + j], ssl[512 + c0 + 4 + j]);
  }
#pragma unroll
  for (int j = 0; j < 8; ++j) sq = fmaf(vals[j], vals[j], sq);
  short8 o;
#pragma unroll
  for (int j = 0; j < 8; ++j) o[j] = f2bf(vals[j]);
  *(short8*)(vbf + (long)r * 512 + c0) = o;
#pragma unroll
  for (int off = 1; off < 64; off <<= 1) sq += __shfl_xor(sq, off);
  float inv = 1.f / (sqrtf(sq) + 1e-8f);
  f32x4 o0, o1;
#pragma unroll
  for (int j = 0; j < 4; ++j) { o0[j] = vals[j] * inv; o1[j] = vals[4 + j] * inv; }
  *(f32x4*)(vn + (long)r * 512 + c0) = o0;
  *(f32x4*)(vn + (long)r * 512 + c0 + 4) = o1;
}

// ---------------- fused GEMM+sim: [0,32) hv ; [32,288) sim ; [288,2336) hx ----------------
// LDS (34816 B): [0,16384) As | [16384,32768) Bs | [32768,34816) csw
// sim aliases: a[16][132] at 0, b[16][132] at 8448.
#define ASP  ((short*)(smem))
#define BSP  ((short*)(smem + 16384))
#define CSW  ((float(*)[2][128])(smem + 32768))
#define SIMA ((float(*)[132])(smem))
#define SIMB ((float(*)[132])(smem + 8448))

__global__ __launch_bounds__(256, 3) void k_gemm(
    const float* __restrict__ x, const short* __restrict__ Wxt,
    const short* __restrict__ vbf, const short* __restrict__ Wvt,
    const float* __restrict__ vn,
    short* __restrict__ Cbf, float* __restrict__ hvr, float* __restrict__ simP,
    float* __restrict__ pstatsX, float* __restrict__ pstatsV) {
  __shared__ char smem[34816];
  int tid = threadIdx.x, lane = tid & 63, wave = tid >> 6;
  int wr = (wave >> 1) * 64, wc = (wave & 1) * 64;

  if (blockIdx.x >= 32 && blockIdx.x < 288) {
    // ---- sim: 128x128 tiles, 8x8/thread, 4-way k-split, k-major LDS ----
    int sid = blockIdx.x - 32;
    int tile = sid >> 2, kh = sid & 3;
    int i0 = (tile >> 3) * 128, j0 = (tile & 7) * 128;
    int row2 = tid >> 1, kg = (tid & 1) * 8;
    int tr = tid >> 4, tc = tid & 15;
    float acc[8][8] = {};
    for (int k0 = kh * 128; k0 < kh * 128 + 128; k0 += 16) {
      __syncthreads();
      f32x4 va0 = *(const f32x4*)(vn + (long)(i0 + row2) * 512 + k0 + kg);
      f32x4 va1 = *(const f32x4*)(vn + (long)(i0 + row2) * 512 + k0 + kg + 4);
      f32x4 vb0 = *(const f32x4*)(vn + (long)(j0 + row2) * 512 + k0 + kg);
      f32x4 vb1 = *(const f32x4*)(vn + (long)(j0 + row2) * 512 + k0 + kg + 4);
#pragma unroll
      for (int j = 0; j < 4; ++j) {
        SIMA[kg + j][row2] = va0[j]; SIMA[kg + 4 + j][row2] = va1[j];
        SIMB[kg + j][row2] = vb0[j]; SIMB[kg + 4 + j][row2] = vb1[j];
      }
      __syncthreads();
#pragma unroll
      for (int k = 0; k < 16; ++k) {
        f32x4 ar0 = *(const f32x4*)&SIMA[k][tr * 8];
        f32x4 ar1 = *(const f32x4*)&SIMA[k][tr * 8 + 4];
        f32x4 br0 = *(const f32x4*)&SIMB[k][tc * 8];
        f32x4 br1 = *(const f32x4*)&SIMB[k][tc * 8 + 4];
        float ar[8], br[8];
#pragma unroll
        for (int j = 0; j < 4; ++j) { ar[j] = ar0[j]; ar[4 + j] = ar1[j]; br[j] = br0[j]; br[4 + j] = br1[j]; }
#pragma unroll
        for (int i = 0; i < 8; ++i)
#pragma unroll
          for (int j = 0; j < 8; ++j)
            acc[i][j] = fmaf(ar[i], br[j], acc[i][j]);
      }
    }
    float* dst = simP + (long)kh * 1048576;
#pragma unroll
    for (int i = 0; i < 8; ++i) {
      f32x4 o0, o1;
#pragma unroll
      for (int j = 0; j < 4; ++j) { o0[j] = acc[i][j]; o1[j] = acc[i][4 + j]; }
      float* rowp = dst + (long)(i0 + tr * 8 + i) * 1024 + j0 + tc * 8;
      *(f32x4*)rowp = o0;
      *(f32x4*)(rowp + 4) = o1;
    }
    return;
  }

  if (blockIdx.x < 32) {
    // ---- hv path: single-buffered m97 pattern ----
    int id = blockIdx.x;                  // mt*8 + nt*2 + mat
    int mt = id >> 3, nt = (id >> 1) & 3, mat = id & 1;
    int m0 = mt * 128, n0 = nt * 128;
    const short* Ab = vbf + ((long)mat * 512 + m0) * 512;
    const short* Bb = Wvt + (long)mat * 262144 + (long)n0 * 512;
    const short* aS[4]; const short* bS[4]; int ldsOff[4];
#pragma unroll
    for (int i = 0; i < 4; ++i) {
      int c = (wave * 4 + i) * 64 + lane;
      int row = c >> 3;
      int ccl = (c & 7) ^ (row & 7);
      aS[i] = Ab + (long)row * 512 + ccl * 8;
      bS[i] = Bb + (long)row * 512 + ccl * 8;
      ldsOff[i] = (wave * 4 + i) * 512;
    }
    f32x4 acc[4][4] = {};
    for (int t = 0; t < 8; ++t) {
      int kn = t * 64;
      __syncthreads();
#pragma unroll
      for (int i = 0; i < 4; ++i) { LDSG(aS[i] + kn, ASP + ldsOff[i]); LDSG(bS[i] + kn, BSP + ldsOff[i]); }
      __syncthreads();
#pragma unroll
      for (int kk = 0; kk < 2; ++kk) {
        int k0 = kk * 32 + (lane >> 4) * 8;
        bf16x8 af[4], bfr[4];
#pragma unroll
        for (int m = 0; m < 4; ++m) {
          int row = wr + m * 16 + (lane & 15);
          int boff = (row * 128 + k0 * 2) ^ ((row & 7) << 4);
          af[m] = *reinterpret_cast<const bf16x8*>((const char*)ASP + boff);
        }
#pragma unroll
        for (int n = 0; n < 4; ++n) {
          int row = wc + n * 16 + (lane & 15);
          int boff = (row * 128 + k0 * 2) ^ ((row & 7) << 4);
          bfr[n] = *reinterpret_cast<const bf16x8*>((const char*)BSP + boff);
        }
#pragma unroll
        for (int m = 0; m < 4; ++m)
#pragma unroll
          for (int n = 0; n < 4; ++n)
            acc[m][n] = __builtin_amdgcn_mfma_f32_16x16x32_bf16(af[m], bfr[n], acc[m][n], 0, 0, 0);
      }
    }
    float* Cb = hvr + (long)mat * 262144;
#pragma unroll
    for (int n = 0; n < 4; ++n) {
      int col = n0 + wc + n * 16 + (lane & 15);
      float s = 0.f, q = 0.f;
#pragma unroll
      for (int m = 0; m < 4; ++m) {
        int row = m0 + wr + m * 16 + ((lane >> 4) << 2);
#pragma unroll
        for (int j = 0; j < 4; ++j) {
          float v = acc[m][n][j];
          s += v; q = fmaf(v, v, q);
          Cb[(long)(row + j) * 512 + col] = v;
        }
      }
      s += __shfl_xor(s, 16); s += __shfl_xor(s, 32);
      q += __shfl_xor(q, 16); q += __shfl_xor(q, 32);
      if (lane < 16) {
        CSW[0][wave >> 1][wc + n * 16 + lane] = s;
        CSW[1][wave >> 1][wc + n * 16 + lane] = q;
      }
    }
    __syncthreads();
    {
      int v = tid >> 7, cl = tid & 127;
      pstatsV[(((long)mat * 4 + mt) * 2 + v) * 512 + n0 + cl] =
          CSW[v][0][cl] + CSW[v][1][cl];
    }
    return;
  }

  // ---- hx path: single-buffer, early A-reg issue ----
  int id = blockIdx.x - 288;
  int w = (id & 7) * 256 + (id >> 3);   // XCD-chunked
  int mt = w >> 3, rres = w & 7;
  int nt = rres & 3, mat = rres >> 2;
  int m0 = mt * 128, n0 = nt * 128;
  const short* Bb = Wxt + (long)mat * 262144 + (long)n0 * 512;

  const float* aSrc[4];
  int aOff[4];
#pragma unroll
  for (int i = 0; i < 4; ++i) {
    int c = i * 256 + tid;
    int row = c >> 3, g = c & 7;
    int rr = m0 + row;
    int b = rr >> 9, p = rr & 511;
    aSrc[i] = x + ((long)(b * 1024 + mat * 512 + p)) * 512 + g * 8;
    aOff[i] = (row * 128 + g * 16) ^ ((row & 7) << 4);
  }
  const short* bSrc[4];
  int ldsOff[4];
#pragma unroll
  for (int i = 0; i < 4; ++i) {
    int c = (wave * 4 + i) * 64 + lane;
    int row = c >> 3;
    int ccl = (c & 7) ^ (row & 7);
    bSrc[i] = Bb + (long)row * 512 + ccl * 8;
    ldsOff[i] = (wave * 4 + i) * 512;
  }
  f32x4 acc[4][4] = {};
  f32x4 a0[4], a1[4];
#pragma unroll
  for (int i = 0; i < 4; ++i) { a0[i] = *(const f32x4*)(aSrc[i]); a1[i] = *(const f32x4*)(aSrc[i] + 4); }

  for (int t = 0; t < 8; ++t) {
    __syncthreads();
#pragma unroll
    for (int i = 0; i < 4; ++i) LDSG(bSrc[i] + t * 64, BSP + ldsOff[i]);
#pragma unroll
    for (int i = 0; i < 4; ++i) {
      short8 o;
#pragma unroll
      for (int j = 0; j < 4; ++j) { o[j] = f2bf(a0[i][j]); o[4 + j] = f2bf(a1[i][j]); }
      *(short8*)((char*)ASP + aOff[i]) = o;
    }
    __syncthreads();
    if (t < 7) {
      int kn = (t + 1) * 64;
#pragma unroll
      for (int i = 0; i < 4; ++i) {
        a0[i] = *(const f32x4*)(aSrc[i] + kn);
        a1[i] = *(const f32x4*)(aSrc[i] + kn + 4);
      }
    }
#pragma unroll
    for (int kk = 0; kk < 2; ++kk) {
      int k0 = kk * 32 + (lane >> 4) * 8;
      bf16x8 af[4], bfr[4];
#pragma unroll
      for (int m = 0; m < 4; ++m) {
        int row = wr + m * 16 + (lane & 15);
        int boff = (row * 128 + k0 * 2) ^ ((row & 7) << 4);
        af[m] = *reinterpret_cast<const bf16x8*>((const char*)ASP + boff);
      }
#pragma unroll
      for (int n = 0; n < 4; ++n) {
        int row = wc + n * 16 + (lane & 15);
        int boff = (row * 128 + k0 * 2) ^ ((row & 7) << 4);
        bfr[n] = *reinterpret_cast<const bf16x8*>((const char*)BSP + boff);
      }
#pragma unroll
      for (int m = 0; m < 4; ++m)
#pragma unroll
        for (int n = 0; n < 4; ++n)
          acc[m][n] = __builtin_amdgcn_mfma_f32_16x16x32_bf16(af[m], bfr[n], acc[m][n], 0, 0, 0);
    }
  }
  short* Cb = Cbf + (long)mat * 32768 * 512;
#pragma unroll
  for (int n = 0; n < 4; ++n) {
    int col = n0 + wc + n * 16 + (lane & 15);
    float s = 0.f, q = 0.f;
#pragma unroll
    for (int m = 0; m < 4; ++m) {
      int row = m0 + wr + m * 16 + ((lane >> 4) << 2);
#pragma unroll
      for (int j = 0; j < 4; ++j) {
        float v = acc[m][n][j];
        s += v; q = fmaf(v, v, q);
        Cb[(long)(row + j) * 512 + col] = f2bf(v);
      }
    }
    s += __shfl_xor(s, 16); s += __shfl_xor(s, 32);
    q += __shfl_xor(q, 16); q += __shfl_xor(q, 32);
    if (lane < 16) {
      CSW[0][wave >> 1][wc + n * 16 + lane] = s;
      CSW[1][wave >> 1][wc + n * 16 + lane] = q;
    }
  }
  __syncthreads();
  {
    int v = tid >> 7, cl = tid & 127;
    pstatsX[(((long)mat * 256 + mt) * 2 + v) * 512 + n0 + cl] =
        CSW[v][0][cl] + CSW[v][1][cl];
  }
}

// ---------------- reduce X and V partials -> ssX, ssV ----------------
__global__ void k_colreduceXV(const float* __restrict__ pstatsX,
                              const float* __restrict__ pstatsV,
                              const float* __restrict__ gx_g, const float* __restrict__ gx_b,
                              const float* __restrict__ gv_g, const float* __restrict__ gv_b,
                              float* __restrict__ ssX, float* __restrict__ ssV) {
  int which = blockIdx.y;
  int c = blockIdx.x * 256 + threadIdx.x;
  if (which < 2) {
    int mat = which;
    float s = 0.f, q = 0.f;
    for (int k = 0; k < 256; ++k) {
      s += pstatsX[(((long)mat * 256 + k) * 2 + 0) * 512 + c];
      q += pstatsX[(((long)mat * 256 + k) * 2 + 1) * 512 + c];
    }
    float mu = s * (1.f / 32768.f);
    float var = fmaxf(q * (1.f / 32768.f) - mu * mu, 0.f);
    float scale = rsqrtf(var + 1e-5f) * gx_g[(long)mat * 512 + c];
    ssX[(mat * 2 + 0) * 512 + c] = scale;
    ssX[(mat * 2 + 1) * 512 + c] = gx_b[(long)mat * 512 + c] - mu * scale;
  } else {
    int mat = which - 2;
    float s = 0.f, q = 0.f;
    for (int k = 0; k < 4; ++k) {
      s += pstatsV[(((long)mat * 4 + k) * 2 + 0) * 512 + c];
      q += pstatsV[(((long)mat * 4 + k) * 2 + 1) * 512 + c];
    }
    float mu = s * (1.f / 512.f);
    float var = fmaxf(q * (1.f / 512.f) - mu * mu, 0.f);
    float scale = rsqrtf(var + 1e-5f) * gv_g[(long)mat * 512 + c];
    ssV[(mat * 2 + 0) * 512 + c] = scale;
    ssV[(mat * 2 + 1) * 512 + c] = gv_b[(long)mat * 512 + c] - mu * scale;
  }
}

// ---------------- fused finalize: [0,256) topk ; [256,384) hv-bcast ; rest hx ----------------
__global__ __launch_bounds__(256) void k_final(
    const short* __restrict__ Cbf, const float* __restrict__ ssX,
    const float* __restrict__ hvr, const float* __restrict__ ssV,
    const float* __restrict__ simP, float* __restrict__ out) {
  int bid = blockIdx.x, tid = threadIdx.x;
  if (bid < 256) {
    // ---- topk: one wave per row ----
    int wv = tid >> 6, lane = tid & 63;
    int row = bid * 4 + wv;
    const float* r0 = simP + (long)row * 1024;
    f32x4 v[4];
#pragma unroll
    for (int i = 0; i < 4; ++i) {
      f32x4 s = *(const f32x4*)(r0 + i * 256 + lane * 4);
#pragma unroll
      for (int h = 1; h < 4; ++h)
        s += *(const f32x4*)(r0 + (long)h * 1048576 + i * 256 + lane * 4);
      v[i] = s;
    }
    float* outIdx = out + 131072L * 512;
    for (int it = 0; it < 30; ++it) {
      float bv = -1e30f; int bi = 1 << 30;
#pragma unroll
      for (int i = 0; i < 4; ++i)
#pragma unroll
        for (int j = 0; j < 4; ++j) {
          float val = v[i][j];
          if (val > bv) { bv = val; bi = i * 256 + lane * 4 + j; }
        }
#pragma unroll
      for (int off = 1; off < 64; off <<= 1) {
        float ov = __shfl_xor(bv, off);
        int oi = __shfl_xor(bi, off);
        if (ov > bv || (ov == bv && oi < bi)) { bv = ov; bi = oi; }
      }
      if (lane == 0) outIdx[(long)row * 30 + it] = (float)bi;
#pragma unroll
      for (int i = 0; i < 4; ++i)
#pragma unroll
        for (int j = 0; j < 4; ++j)
          if ((i * 256 + lane * 4 + j) == bi) v[i][j] = -1e30f;
    }
  } else if (bid < 384) {
    // ---- hv broadcast: one block per (mat,b), contiguous 1 MB stream ----
    int b_ = bid - 256;
    int mat = b_ >> 6, bb = b_ & 63;
    int d = (tid & 127) * 4, pr = tid >> 7;
    f32x4 sc = *(const f32x4*)(ssV + ((long)mat * 2 + 0) * 512 + d);
    f32x4 sh = *(const f32x4*)(ssV + ((long)mat * 2 + 1) * 512 + d);
    const float* src = hvr + (long)mat * 262144;
    float* dst = out + 65536L * 512 + ((long)(mat * 64 + bb)) * 262144;
    for (int p0 = 0; p0 < 512; p0 += 2) {
      int p = p0 + pr;
      f32x4 h = *(const f32x4*)(src + (long)p * 512 + d);
      f32x4 o;
#pragma unroll
      for (int j = 0; j < 4; ++j) o[j] = fmaf(h[j], sc[j], sh[j]);
      *(f32x4*)(dst + (long)p * 512 + d) = o;
    }
  } else {
    // ---- hx finalize: bf16 -> BN -> f32 ----
    long e = (long)(bid - 384) * 256 + tid;   // 8-elem chunk
    long row = e >> 6;
    int c0 = (int)(e & 63) * 8;
    int mat = (int)(row >> 15);
    short8 h = *(const short8*)(Cbf + row * 512 + c0);
    const float* sb = ssX + mat * 1024;
    f32x4 o0, o1;
#pragma unroll
    for (int j = 0; j < 4; ++j) o0[j] = fmaf(bf2f(h[j]), sb[c0 + j], sb[512 + c0 + j]);
#pragma unroll
    for (int j = 0; j < 4; ++j) o1[j] = fmaf(bf2f(h[4 + j]), sb[c0 + 4 + j], sb[512 + c0 + 4 + j]);
    *(f32x4*)(out + row * 512 + c0) = o0;
    *(f32x4*)(out + row * 512 + c0 + 4) = o1;
  }
}

extern "C" void kernel_launch(void* const* d_in, const int* in_sizes, int n_in,
                              void* d_out, int out_size, void* d_ws, size_t ws_size,
                              hipStream_t stream) {
  (void)in_sizes; (void)n_in; (void)out_size; (void)ws_size;
  const float* x     = (const float*)d_in[0];
  const float* emb   = (const float*)d_in[1];
  const float* emb_g = (const float*)d_in[2];
  const float* emb_b = (const float*)d_in[3];
  const float* Wx    = (const float*)d_in[4];
  // d_in[5] = bx : cancels in BN
  const float* gx_g  = (const float*)d_in[6];
  const float* gx_b  = (const float*)d_in[7];
  const float* Wv    = (const float*)d_in[8];
  // d_in[9] = bv : cancels in BN
  const float* gv_g  = (const float*)d_in[10];
  const float* gv_b  = (const float*)d_in[11];
  float* out = (float*)d_out;

  char* ws = (char*)d_ws;
  short* hxr = (short*)ws;  ws += 65536L * 512 * 2;       // 67.1 MB
  short* Wxt = (short*)ws;  ws += 2L * 512 * 512 * 2;
  short* Wvt = (short*)ws;  ws += 2L * 512 * 512 * 2;
  short* vbf = (short*)ws;  ws += 1024L * 512 * 2;
  float* vn  = (float*)ws;  ws += 1024L * 512 * 4;
  float* hvr = (float*)ws;  ws += 2L * 512 * 512 * 4;
  float* simP = (float*)ws; ws += 4L * 1024 * 1024 * 4;   // 16 MB
  float* pstatsX = (float*)ws; ws += 2L * 256 * 2 * 512 * 4;
  float* pstatsE = (float*)ws; ws += 16L * 2 * 512 * 4;
  float* pstatsV = (float*)ws; ws += 2L * 4 * 2 * 512 * 4;
  float* ssX = (float*)ws;     ws += 4L * 512 * 4;
  float* ssV = (float*)ws;     ws += 4L * 512 * 4;

  k_prep<<<272, 256, 0, stream>>>(Wx, Wv, emb, Wxt, Wvt, pstatsE);
  k_compute_v<<<256, 256, 0, stream>>>(emb, pstatsE, emb_g, emb_b, vbf, vn);
  k_gemm<<<2336, 256, 0, stream>>>(x, Wxt, vbf, Wvt, vn, hxr, hvr, simP, pstatsX, pstatsV);
  k_colreduceXV<<<dim3(2, 4), 256, 0, stream>>>(pstatsX, pstatsV, gx_g, gx_b, gv_g, gv_b, ssX, ssV);
  k_final<<<16768, 256, 0, stream>>>(hxr, ssX, hvr, ssV, simP, out);
}